// Round 10
// baseline (268.684 us; speedup 1.0000x reference)
//
#include <hip/hip_runtime.h>
#include <hip/hip_bf16.h>

// Problem constants (static per reference)
#define D 128
#define H 64
#define R 4
#define LDC 132    // LDS stride (floats) for the per-group strip

// MFMA fragment types
typedef __attribute__((ext_vector_type(8))) short bf16x8;
typedef __attribute__((ext_vector_type(4))) float f32x4;

// Weight-prep layout: per relation, 56 frags of 512 bf16 elems (64 lanes x 8):
//   W1 frags [0,16), W2 [16,24), W3 [24,40), Wu1_{r+1} [40,56)
// Updater block appended at UBASE: Wu1[0:128] [0,16), Wu2 [16,24), Wu3 [24,40)
// Frag f = ntile*KSTEPS + kstep; lane l covers col = ntile*16+(l&15),
// k = kstep*32 + (l>>4)*8 + i.  (Same phi used for A -> phi cancels.)
#define PREL 56
#define PFRAG 512
#define UBASE (R * PREL)     // 224
#define UPREL 40
#define NFRAG (UBASE + UPREL)

__device__ __forceinline__ float4 relu4(float4 v) {
    return make_float4(fmaxf(v.x, 0.f), fmaxf(v.y, 0.f), fmaxf(v.z, 0.f), fmaxf(v.w, 0.f));
}

// split fp32 -> bf16 hi (RTZ) + bf16 lo (residual, RTZ)
__device__ __forceinline__ void split1(float x, short& hi, short& lo) {
    unsigned u = __float_as_uint(x);
    unsigned hb = u & 0xffff0000u;
    float res = x - __uint_as_float(hb);
    hi = (short)(u >> 16);
    lo = (short)(__float_as_uint(res) >> 16);
}

__device__ __forceinline__ void split8(const float* x8, bf16x8& hi, bf16x8& lo) {
#pragma unroll
    for (int i = 0; i < 8; ++i) {
        short h, l;
        split1(x8[i], h, l);
        hi[i] = h; lo[i] = l;
    }
}

__device__ __forceinline__ void load_split_A(const float* ap, bf16x8& ah, bf16x8& al) {
    float x8[8];
    *(float4*)&x8[0] = *(const float4*)ap;
    *(float4*)&x8[4] = *(const float4*)(ap + 4);
    split8(x8, ah, al);
}

// Single-stream: A from LDS fp32 (split on the fly), B pre-split global, batched loads.
template<int NT_TILES, int KSTEPS>
__device__ __forceinline__ void mfma_layer(const float* Als, int ld,
                                           const short* __restrict__ Bhi,
                                           const short* __restrict__ Blo,
                                           int lane, f32x4* acc) {
#pragma unroll
    for (int ks = 0; ks < KSTEPS; ++ks) {
        bf16x8 ah, al;
        load_split_A(Als + (lane & 15) * ld + ks * 32 + ((lane >> 4) << 3), ah, al);
        bf16x8 bh[NT_TILES], bl[NT_TILES];
#pragma unroll
        for (int n = 0; n < NT_TILES; ++n) {
            int f = n * KSTEPS + ks;
            bh[n] = *(const bf16x8*)(Bhi + (((size_t)f * 64 + lane) << 3));
            bl[n] = *(const bf16x8*)(Blo + (((size_t)f * 64 + lane) << 3));
        }
#pragma unroll
        for (int n = 0; n < NT_TILES; ++n) {
            acc[n] = __builtin_amdgcn_mfma_f32_16x16x32_bf16(ah, bh[n], acc[n], 0, 0, 0);
            acc[n] = __builtin_amdgcn_mfma_f32_16x16x32_bf16(ah, bl[n], acc[n], 0, 0, 0);
            acc[n] = __builtin_amdgcn_mfma_f32_16x16x32_bf16(al, bh[n], acc[n], 0, 0, 0);
        }
    }
}

// Dual-stream: two A strips share each B-fragment pair (6 MFMAs per pair).
template<int NT_TILES, int KSTEPS>
__device__ __forceinline__ void mfma_layer_dual(const float* A0, const float* A1, int ld,
                                                const short* __restrict__ Bhi,
                                                const short* __restrict__ Blo,
                                                int lane, f32x4* acc0, f32x4* acc1) {
#pragma unroll
    for (int ks = 0; ks < KSTEPS; ++ks) {
        bf16x8 ah0, al0, ah1, al1;
        load_split_A(A0 + (lane & 15) * ld + ks * 32 + ((lane >> 4) << 3), ah0, al0);
        load_split_A(A1 + (lane & 15) * ld + ks * 32 + ((lane >> 4) << 3), ah1, al1);
        bf16x8 bh[NT_TILES], bl[NT_TILES];
#pragma unroll
        for (int n = 0; n < NT_TILES; ++n) {
            int f = n * KSTEPS + ks;
            bh[n] = *(const bf16x8*)(Bhi + (((size_t)f * 64 + lane) << 3));
            bl[n] = *(const bf16x8*)(Blo + (((size_t)f * 64 + lane) << 3));
        }
#pragma unroll
        for (int n = 0; n < NT_TILES; ++n) {
            acc0[n] = __builtin_amdgcn_mfma_f32_16x16x32_bf16(ah0, bh[n], acc0[n], 0, 0, 0);
            acc1[n] = __builtin_amdgcn_mfma_f32_16x16x32_bf16(ah1, bh[n], acc1[n], 0, 0, 0);
            acc0[n] = __builtin_amdgcn_mfma_f32_16x16x32_bf16(ah0, bl[n], acc0[n], 0, 0, 0);
            acc1[n] = __builtin_amdgcn_mfma_f32_16x16x32_bf16(ah1, bl[n], acc1[n], 0, 0, 0);
            acc0[n] = __builtin_amdgcn_mfma_f32_16x16x32_bf16(al0, bh[n], acc0[n], 0, 0, 0);
            acc1[n] = __builtin_amdgcn_mfma_f32_16x16x32_bf16(al1, bh[n], acc1[n], 0, 0, 0);
        }
    }
}

// Dual-stream with register A (layer 1).
template<int NT_TILES, int KSTEPS>
__device__ __forceinline__ void mfma_layer_regA_dual(const bf16x8* ah0, const bf16x8* al0,
                                                     const bf16x8* ah1, const bf16x8* al1,
                                                     const short* __restrict__ Bhi,
                                                     const short* __restrict__ Blo,
                                                     int lane, f32x4* acc0, f32x4* acc1) {
#pragma unroll
    for (int ks = 0; ks < KSTEPS; ++ks) {
        bf16x8 bh[NT_TILES], bl[NT_TILES];
#pragma unroll
        for (int n = 0; n < NT_TILES; ++n) {
            int f = n * KSTEPS + ks;
            bh[n] = *(const bf16x8*)(Bhi + (((size_t)f * 64 + lane) << 3));
            bl[n] = *(const bf16x8*)(Blo + (((size_t)f * 64 + lane) << 3));
        }
#pragma unroll
        for (int n = 0; n < NT_TILES; ++n) {
            acc0[n] = __builtin_amdgcn_mfma_f32_16x16x32_bf16(ah0[ks], bh[n], acc0[n], 0, 0, 0);
            acc1[n] = __builtin_amdgcn_mfma_f32_16x16x32_bf16(ah1[ks], bh[n], acc1[n], 0, 0, 0);
            acc0[n] = __builtin_amdgcn_mfma_f32_16x16x32_bf16(ah0[ks], bl[n], acc0[n], 0, 0, 0);
            acc1[n] = __builtin_amdgcn_mfma_f32_16x16x32_bf16(ah1[ks], bl[n], acc1[n], 0, 0, 0);
            acc0[n] = __builtin_amdgcn_mfma_f32_16x16x32_bf16(al0[ks], bh[n], acc0[n], 0, 0, 0);
            acc1[n] = __builtin_amdgcn_mfma_f32_16x16x32_bf16(al1[ks], bh[n], acc1[n], 0, 0, 0);
        }
    }
}

// Single-stream with register A (k_upd layer 1).
template<int NT_TILES, int KSTEPS>
__device__ __forceinline__ void mfma_layer_regA(const bf16x8* ah, const bf16x8* al,
                                                const short* __restrict__ Bhi,
                                                const short* __restrict__ Blo,
                                                int lane, f32x4* acc) {
#pragma unroll
    for (int ks = 0; ks < KSTEPS; ++ks) {
        bf16x8 bh[NT_TILES], bl[NT_TILES];
#pragma unroll
        for (int n = 0; n < NT_TILES; ++n) {
            int f = n * KSTEPS + ks;
            bh[n] = *(const bf16x8*)(Bhi + (((size_t)f * 64 + lane) << 3));
            bl[n] = *(const bf16x8*)(Blo + (((size_t)f * 64 + lane) << 3));
        }
#pragma unroll
        for (int n = 0; n < NT_TILES; ++n) {
            acc[n] = __builtin_amdgcn_mfma_f32_16x16x32_bf16(ah[ks], bh[n], acc[n], 0, 0, 0);
            acc[n] = __builtin_amdgcn_mfma_f32_16x16x32_bf16(ah[ks], bl[n], acc[n], 0, 0, 0);
            acc[n] = __builtin_amdgcn_mfma_f32_16x16x32_bf16(al[ks], bh[n], acc[n], 0, 0, 0);
        }
    }
}

// bias + relu + store C strip to LDS fp32 (C/D layout: col=lane&15, row=(lane>>4)*4+reg)
template<int NT_TILES>
__device__ __forceinline__ void store_C_lds(const f32x4* acc, const float* __restrict__ bias,
                                            float* Ld, int ld, int lane) {
    int r0 = (lane >> 4) << 2;
#pragma unroll
    for (int n = 0; n < NT_TILES; ++n) {
        int col = n * 16 + (lane & 15);
        float bv = bias[col];
#pragma unroll
        for (int q = 0; q < 4; ++q)
            Ld[(r0 + q) * ld + col] = fmaxf(acc[n][q] + bv, 0.f);
    }
}

// ---------------- CSR build ----------------

__global__ __launch_bounds__(256) void k_count(const int* __restrict__ dst, int* __restrict__ cnt, int E) {
    int e = blockIdx.x * 256 + threadIdx.x;
    if (e < E) atomicAdd(&cnt[dst[e]], 1);
}

__global__ __launch_bounds__(256) void k_blocksum(const int* __restrict__ cnt,
                                                  int* __restrict__ bsum, int N) {
    __shared__ int red[256];
    int i = blockIdx.x * 256 + threadIdx.x;
    red[threadIdx.x] = (i < N) ? cnt[i] : 0;
    __syncthreads();
    for (int off = 128; off > 0; off >>= 1) {
        if (threadIdx.x < off) red[threadIdx.x] += red[threadIdx.x + off];
        __syncthreads();
    }
    if (threadIdx.x == 0) bsum[blockIdx.x] = red[0];
}

__global__ __launch_bounds__(1024) void k_scan_bsums(int* __restrict__ bsum, int G) {
    __shared__ int s[1024];
    int t = threadIdx.x;
    int v = (t < G) ? bsum[t] : 0;
    s[t] = v;
    __syncthreads();
    for (int off = 1; off < 1024; off <<= 1) {
        int u = (t >= off) ? s[t - off] : 0;
        __syncthreads();
        s[t] += u;
        __syncthreads();
    }
    if (t < G) bsum[t] = s[t] - v;   // exclusive
}

__global__ __launch_bounds__(256) void k_scan_offs(const int* __restrict__ cnt,
                                                   const int* __restrict__ bsum,
                                                   int* __restrict__ offs,
                                                   int* __restrict__ cursor, int N) {
    __shared__ int s[256];
    int t = threadIdx.x;
    int i = blockIdx.x * 256 + t;
    int v = (i < N) ? cnt[i] : 0;
    s[t] = v;
    __syncthreads();
    for (int off = 1; off < 256; off <<= 1) {
        int u = (t >= off) ? s[t - off] : 0;
        __syncthreads();
        s[t] += u;
        __syncthreads();
    }
    if (i < N) {
        int e = s[t] - v + bsum[blockIdx.x];
        offs[i] = e;
        cursor[i] = e;
    }
}

__global__ __launch_bounds__(256) void k_fill(const int* __restrict__ src, const int* __restrict__ dst,
                                              const int* __restrict__ etype, int* __restrict__ cursor,
                                              int* __restrict__ eidx, int E) {
    int e = blockIdx.x * 256 + threadIdx.x;
    if (e < E) {
        int d = dst[e];
        int p = atomicAdd(&cursor[d], 1);
        eidx[p] = src[e] * 4 + etype[e];
    }
}

// ---------------- Weight prep: split + frag-swizzle all B matrices ----------------

__global__ __launch_bounds__(256) void k_wprep(
    const float* __restrict__ W1, const float* __restrict__ W2,
    const float* __restrict__ W3, const float* __restrict__ Wu1,
    const float* __restrict__ Wu2, const float* __restrict__ Wu3,
    short* __restrict__ Phi, short* __restrict__ Plo)
{
    int pair = blockIdx.x;
    const float* src; int KS, NTl, fragbase, ncol;
    if (pair < 16) {
        int r = pair >> 2, mat = pair & 3;
        if (mat == 0)      { src = W1  + (size_t)r * (D * H);       KS = 4; NTl = 4; fragbase = r * PREL + 0;  ncol = 64;  }
        else if (mat == 1) { src = W2  + (size_t)r * (H * H);       KS = 2; NTl = 4; fragbase = r * PREL + 16; ncol = 64;  }
        else if (mat == 2) { src = W3  + (size_t)r * (H * D);       KS = 2; NTl = 8; fragbase = r * PREL + 24; ncol = 128; }
        else               { src = Wu1 + (size_t)(r + 1) * D * H;   KS = 4; NTl = 4; fragbase = r * PREL + 40; ncol = 64;  }
    } else {
        int mat = pair - 16;
        if (mat == 0)      { src = Wu1; KS = 4; NTl = 4; fragbase = UBASE + 0;  ncol = 64;  }  // rows 0..127
        else if (mat == 1) { src = Wu2; KS = 2; NTl = 4; fragbase = UBASE + 16; ncol = 64;  }
        else               { src = Wu3; KS = 2; NTl = 8; fragbase = UBASE + 24; ncol = 128; }
    }
    int nf = NTl * KS;
    for (int u = threadIdx.x; u < nf * 64; u += 256) {
        int f = u >> 6, lane = u & 63;
        int n = f / KS, ks = f - n * KS;
        int col = n * 16 + (lane & 15);
        int k0 = ks * 32 + ((lane >> 4) << 3);
        size_t dstp = (((size_t)(fragbase + f)) * 64 + (size_t)lane) * 8;
#pragma unroll
        for (int i = 0; i < 8; ++i) {
            short h, l;
            split1(src[(size_t)(k0 + i) * ncol + col], h, l);
            Phi[dstp + i] = h;
            Plo[dstp + i] = l;
        }
    }
}

// ---------------- Stage A: per-(tile, relation) message MLP + Wu1 fold ----------------
// Block = 128 threads (2 waves) covering 64 nodes; each wave owns 32 rows as
// TWO 16-row groups sharing every B-fragment load (6 MFMAs per B pair) with
// dual accumulator streams for in-wave ILP. Wave-private LDS strips (2 per
// wave, 16x132 each), barrier-free. 33792 B LDS => 4 blocks/CU.

__global__ __launch_bounds__(128) void k_mlp_rel(
    const float* __restrict__ X,
    const float* __restrict__ b1, const float* __restrict__ b2, const float* __restrict__ b3,
    const short* __restrict__ Phi, const short* __restrict__ Plo,
    float* __restrict__ U, int N)
{
    __shared__ float Bsh[64 * LDC];   // 2 waves x 2 groups x 16 rows

    const int tid = threadIdx.x;
    const int lane = tid & 63;
    const int w = tid >> 6;          // 0..1
    const int r = blockIdx.x & 3;
    const int n0 = (blockIdx.x >> 2) * 64;
    const int g0row = n0 + w * 32;         // group 0 base node
    const int g1row = g0row + 16;          // group 1 base node

    const short* PH = Phi + (size_t)(r * PREL) * PFRAG;
    const short* PL = Plo + (size_t)(r * PREL) * PFRAG;
    const float* b1r = b1 + r * H;
    const float* b2r = b2 + r * H;
    const float* b3r = b3 + r * D;

    float* S0 = &Bsh[(w * 32) * LDC];
    float* S1 = &Bsh[(w * 32 + 16) * LDC];

    // stage X A-fragments for both groups direct from global, split once
    bf16x8 ah0[4], al0[4], ah1[4], al1[4];
    {
        int row0 = g0row + (lane & 15);
        int row1 = g1row + (lane & 15);
        const float* xp0 = X + (size_t)row0 * D + ((lane >> 4) << 3);
        const float* xp1 = X + (size_t)row1 * D + ((lane >> 4) << 3);
        bool ok0 = (row0 < N), ok1 = (row1 < N);
#pragma unroll
        for (int ks = 0; ks < 4; ++ks) {
            float x8[8];
            if (ok0) {
                *(float4*)&x8[0] = *(const float4*)(xp0 + ks * 32);
                *(float4*)&x8[4] = *(const float4*)(xp0 + ks * 32 + 4);
            } else {
#pragma unroll
                for (int i = 0; i < 8; ++i) x8[i] = 0.f;
            }
            split8(x8, ah0[ks], al0[ks]);
            if (ok1) {
                *(float4*)&x8[0] = *(const float4*)(xp1 + ks * 32);
                *(float4*)&x8[4] = *(const float4*)(xp1 + ks * 32 + 4);
            } else {
#pragma unroll
                for (int i = 0; i < 8; ++i) x8[i] = 0.f;
            }
            split8(x8, ah1[ks], al1[ks]);
        }
    }

    // layer 1: X(32x128) @ W1(128x64) — A from registers, dual stream
    f32x4 acc0[8], acc1[8];
#pragma unroll
    for (int n = 0; n < 4; ++n) { acc0[n] = (f32x4){0.f,0.f,0.f,0.f}; acc1[n] = (f32x4){0.f,0.f,0.f,0.f}; }
    mfma_layer_regA_dual<4, 4>(ah0, al0, ah1, al1, PH, PL, lane, acc0, acc1);
    store_C_lds<4>(acc0, b1r, S0, LDC, lane);
    store_C_lds<4>(acc1, b1r, S1, LDC, lane);   // H1

    // layer 2: H1 @ W2(64x64) -> H2 (in place)
#pragma unroll
    for (int n = 0; n < 4; ++n) { acc0[n] = (f32x4){0.f,0.f,0.f,0.f}; acc1[n] = (f32x4){0.f,0.f,0.f,0.f}; }
    mfma_layer_dual<4, 2>(S0, S1, LDC, PH + (size_t)16 * PFRAG, PL + (size_t)16 * PFRAG, lane, acc0, acc1);
    store_C_lds<4>(acc0, b2r, S0, LDC, lane);
    store_C_lds<4>(acc1, b2r, S1, LDC, lane);   // H2

    // layer 3: H2 @ W3(64x128), relu -> T (same strips)
#pragma unroll
    for (int n = 0; n < 8; ++n) { acc0[n] = (f32x4){0.f,0.f,0.f,0.f}; acc1[n] = (f32x4){0.f,0.f,0.f,0.f}; }
    mfma_layer_dual<8, 2>(S0, S1, LDC, PH + (size_t)24 * PFRAG, PL + (size_t)24 * PFRAG, lane, acc0, acc1);
    store_C_lds<8>(acc0, b3r, S0, LDC, lane);
    store_C_lds<8>(acc1, b3r, S1, LDC, lane);   // T

    // U projection: T(32x128) @ Wu1_{r+1}(128x64)
#pragma unroll
    for (int n = 0; n < 4; ++n) { acc0[n] = (f32x4){0.f,0.f,0.f,0.f}; acc1[n] = (f32x4){0.f,0.f,0.f,0.f}; }
    mfma_layer_dual<4, 4>(S0, S1, LDC, PH + (size_t)40 * PFRAG, PL + (size_t)40 * PFRAG, lane, acc0, acc1);
    {
        int r0 = (lane >> 4) << 2;
#pragma unroll
        for (int n = 0; n < 4; ++n) {
            int col = n * 16 + (lane & 15);
#pragma unroll
            for (int q = 0; q < 4; ++q) {
                int node0 = g0row + r0 + q;
                int node1 = g1row + r0 + q;
                if (node0 < N) U[((size_t)node0 * R + r) * H + col] = acc0[n][q];
                if (node1 < N) U[((size_t)node1 * R + r) * H + col] = acc1[n][q];
            }
        }
    }
}

// ---------------- Stage B: gather S[n] = sum over in-edges of U[src*4+rel] ----------------

__global__ __launch_bounds__(256) void k_gather(
    const float* __restrict__ U,
    const int* __restrict__ cnt, const int* __restrict__ offs, const int* __restrict__ eidx,
    float* __restrict__ S, int N)
{
    const int wid = threadIdx.x >> 6, lane = threadIdx.x & 63;
    const int n = blockIdx.x * 4 + wid;
    if (n >= N) return;
    const int g = cnt[n];
    const int s = offs[n];
    float acc = 0.f;
    for (int base = 0; base < g; base += 64) {
        int m = g - base; if (m > 64) m = 64;
        int v = 0;
        if (lane < m) v = eidx[s + base + lane];
        for (int j0 = 0; j0 < m; j0 += 8) {
            int lim = m - j0; if (lim > 8) lim = 8;
            float t[8];
#pragma unroll
            for (int j = 0; j < 8; ++j) {
                int vi = __shfl(v, j0 + j);
                t[j] = (j < lim) ? U[(size_t)vi * H + lane] : 0.f;
            }
#pragma unroll
            for (int j = 0; j < 8; ++j) acc += t[j];
        }
    }
    S[(size_t)n * H + lane] = acc;
}

// ---------------- Stage C: updater MLP + select (split-bf16 MFMA, barrier-free) ----------------

__global__ __launch_bounds__(256) void k_upd(
    const float* __restrict__ X, const float* __restrict__ S,
    const int* __restrict__ cnt, const int* __restrict__ node_type,
    const short* __restrict__ Phi, const short* __restrict__ Plo,
    const float* __restrict__ bu1, const float* __restrict__ bu2, const float* __restrict__ bu3,
    float* __restrict__ out, int N)
{
    __shared__ float Hsh[64 * LDC];   // per-wave strips (H1/H2)

    const int tid = threadIdx.x;
    const int lane = tid & 63;
    const int w = tid >> 6;
    const int m16 = w * 16;
    const int n0 = blockIdx.x * 64;

    const short* PH = Phi + (size_t)UBASE * PFRAG;
    const short* PL = Plo + (size_t)UBASE * PFRAG;

    float* Ws = &Hsh[m16 * LDC];

    // stage chunk0 = relu(x) * (indeg > 0) direct into register A-fragments
    bf16x8 ahx[4], alx[4];
    {
        int row = n0 + m16 + (lane & 15);
        bool ok = (row < N) && (cnt[row] > 0);
        const float* xp = X + (size_t)row * D + ((lane >> 4) << 3);
#pragma unroll
        for (int ks = 0; ks < 4; ++ks) {
            float x8[8];
            if (ok) {
                float4 a = *(const float4*)(xp + ks * 32);
                float4 b = *(const float4*)(xp + ks * 32 + 4);
                a = relu4(a); b = relu4(b);
                *(float4*)&x8[0] = a;
                *(float4*)&x8[4] = b;
            } else {
#pragma unroll
                for (int i = 0; i < 8; ++i) x8[i] = 0.f;
            }
            split8(x8, ahx[ks], alx[ks]);
        }
    }

    // layer 1: chunk0 @ Wu1[0:128] + S + bu1, relu -> H1
    f32x4 acc[8];
#pragma unroll
    for (int n = 0; n < 4; ++n) acc[n] = (f32x4){0.f, 0.f, 0.f, 0.f};
    mfma_layer_regA<4, 4>(ahx, alx, PH, PL, lane, acc);
    {
        int r0 = (lane >> 4) << 2;
#pragma unroll
        for (int n = 0; n < 4; ++n) {
            int col = n * 16 + (lane & 15);
            float bv = bu1[col];
#pragma unroll
            for (int q = 0; q < 4; ++q) {
                int node = n0 + m16 + r0 + q;
                float sv = (node < N) ? S[(size_t)node * H + col] : 0.f;
                Ws[(r0 + q) * LDC + col] = fmaxf(acc[n][q] + bv + sv, 0.f);
            }
        }
    }

    // layer 2: H1 @ Wu2, relu -> H2 (in place)
#pragma unroll
    for (int n = 0; n < 4; ++n) acc[n] = (f32x4){0.f, 0.f, 0.f, 0.f};
    mfma_layer<4, 2>(Ws, LDC, PH + (size_t)16 * PFRAG, PL + (size_t)16 * PFRAG, lane, acc);
    store_C_lds<4>(acc, bu2, Ws, LDC, lane);

    // layer 3: H2 @ Wu3 (linear) + select by node_type
#pragma unroll
    for (int n = 0; n < 8; ++n) acc[n] = (f32x4){0.f, 0.f, 0.f, 0.f};
    mfma_layer<8, 2>(Ws, LDC, PH + (size_t)24 * PFRAG, PL + (size_t)24 * PFRAG, lane, acc);
    {
        int r0 = (lane >> 4) << 2;
#pragma unroll
        for (int q = 0; q < 4; ++q) {
            int node = n0 + m16 + r0 + q;
            if (node >= N) continue;
            int t = node_type[node];
#pragma unroll
            for (int n = 0; n < 8; ++n) {
                int col = n * 16 + (lane & 15);
                float o = (t <= 1) ? (acc[n][q] + bu3[col])
                                   : X[(size_t)node * D + col];
                out[(size_t)node * D + col] = o;
            }
        }
    }
}

extern "C" void kernel_launch(void* const* d_in, const int* in_sizes, int n_in,
                              void* d_out, int out_size, void* d_ws, size_t ws_size,
                              hipStream_t stream) {
    const float* X     = (const float*)d_in[0];
    const int*   src   = (const int*)d_in[1];
    const int*   dst   = (const int*)d_in[2];
    const int*   etype = (const int*)d_in[3];
    const int*   ntype = (const int*)d_in[4];
    const float* W1    = (const float*)d_in[5];
    const float* b1    = (const float*)d_in[6];
    const float* W2    = (const float*)d_in[7];
    const float* b2    = (const float*)d_in[8];
    const float* W3    = (const float*)d_in[9];
    const float* b3    = (const float*)d_in[10];
    const float* Wu1   = (const float*)d_in[11];
    const float* bu1   = (const float*)d_in[12];
    const float* Wu2   = (const float*)d_in[13];
    const float* bu2   = (const float*)d_in[14];
    const float* Wu3   = (const float*)d_in[15];
    const float* bu3   = (const float*)d_in[16];
    float* out = (float*)d_out;

    const int N = in_sizes[4];
    const int E = in_sizes[1];

    // workspace layout
    float* U    = (float*)d_ws;                       // N*R*H floats (51.2 MB)
    float* S    = U + (size_t)N * R * H;              // N*H floats (12.8 MB)
    int* cnt    = (int*)(S + (size_t)N * H);          // N
    int* offs   = cnt + N;                            // N
    int* cursor = offs + N;                           // N
    int* eidx   = cursor + N;                         // E
    short* Phi  = (short*)(eidx + E);                 // NFRAG*PFRAG shorts
    short* Plo  = Phi + (size_t)NFRAG * PFRAG;
    int* bsum   = (int*)(Plo + (size_t)NFRAG * PFRAG);  // ceil(N/256)

    hipMemsetAsync(cnt, 0, (size_t)N * sizeof(int), stream);

    int eb = (E + 255) / 256;
    int G = (N + 255) / 256;
    k_count<<<eb, 256, 0, stream>>>(dst, cnt, E);
    k_blocksum<<<G, 256, 0, stream>>>(cnt, bsum, N);
    k_scan_bsums<<<1, 1024, 0, stream>>>(bsum, G);
    k_scan_offs<<<G, 256, 0, stream>>>(cnt, bsum, offs, cursor, N);
    k_fill<<<eb, 256, 0, stream>>>(src, dst, etype, cursor, eidx, E);
    k_wprep<<<19, 256, 0, stream>>>(W1, W2, W3, Wu1, Wu2, Wu3, Phi, Plo);

    int tiles = (N + 63) / 64;
    k_mlp_rel<<<tiles * R, 128, 0, stream>>>(X, b1, b2, b3, Phi, Plo, U, N);
    k_gather<<<(N + 3) / 4, 256, 0, stream>>>(U, cnt, offs, eidx, S, N);
    k_upd<<<tiles, 256, 0, stream>>>(X, S, cnt, ntype, Phi, Plo, bu1, bu2, bu3, out, N);
}

// Round 11
// 243.246 us; speedup vs baseline: 1.1046x; 1.1046x over previous
//
#include <hip/hip_runtime.h>
#include <hip/hip_bf16.h>

// Problem constants (static per reference)
#define D 128
#define H 64
#define R 4
#define NT 64      // nodes per tile/block (4 waves x 16 rows)
#define LDC 132    // LDS stride (floats) for the per-wave strip

// MFMA fragment types
typedef __attribute__((ext_vector_type(8))) short bf16x8;
typedef __attribute__((ext_vector_type(4))) float f32x4;

// Weight-prep layout: per relation, 56 frags of 512 bf16 elems (64 lanes x 8):
//   W1 frags [0,16), W2 [16,24), W3 [24,40), Wu1_{r+1} [40,56)
// Updater block appended at UBASE: Wu1[0:128] [0,16), Wu2 [16,24), Wu3 [24,40)
// Frag f = ntile*KSTEPS + kstep; lane l covers col = ntile*16+(l&15),
// k = kstep*32 + (l>>4)*8 + i.  (Same phi used for A -> phi cancels.)
#define PREL 56
#define PFRAG 512
#define UBASE (R * PREL)     // 224
#define UPREL 40
#define NFRAG (UBASE + UPREL)

__device__ __forceinline__ float4 relu4(float4 v) {
    return make_float4(fmaxf(v.x, 0.f), fmaxf(v.y, 0.f), fmaxf(v.z, 0.f), fmaxf(v.w, 0.f));
}

// split fp32 -> bf16 hi (RTZ) + bf16 lo (residual, RTZ)
__device__ __forceinline__ void split1(float x, short& hi, short& lo) {
    unsigned u = __float_as_uint(x);
    unsigned hb = u & 0xffff0000u;
    float res = x - __uint_as_float(hb);
    hi = (short)(u >> 16);
    lo = (short)(__float_as_uint(res) >> 16);
}

__device__ __forceinline__ void split8(const float* x8, bf16x8& hi, bf16x8& lo) {
#pragma unroll
    for (int i = 0; i < 8; ++i) {
        short h, l;
        split1(x8[i], h, l);
        hi[i] = h; lo[i] = l;
    }
}

__device__ __forceinline__ void load_split_A(const float* ap, bf16x8& ah, bf16x8& al) {
    float x8[8];
    *(float4*)&x8[0] = *(const float4*)ap;
    *(float4*)&x8[4] = *(const float4*)(ap + 4);
    split8(x8, ah, al);
}

// Single-stream: A from LDS fp32 (split on the fly), B pre-split global, batched loads.
template<int NT_TILES, int KSTEPS>
__device__ __forceinline__ void mfma_layer(const float* Als, int ld,
                                           const short* __restrict__ Bhi,
                                           const short* __restrict__ Blo,
                                           int lane, f32x4* acc) {
#pragma unroll
    for (int ks = 0; ks < KSTEPS; ++ks) {
        bf16x8 ah, al;
        load_split_A(Als + (lane & 15) * ld + ks * 32 + ((lane >> 4) << 3), ah, al);
        bf16x8 bh[NT_TILES], bl[NT_TILES];
#pragma unroll
        for (int n = 0; n < NT_TILES; ++n) {
            int f = n * KSTEPS + ks;
            bh[n] = *(const bf16x8*)(Bhi + (((size_t)f * 64 + lane) << 3));
            bl[n] = *(const bf16x8*)(Blo + (((size_t)f * 64 + lane) << 3));
        }
#pragma unroll
        for (int n = 0; n < NT_TILES; ++n) {
            acc[n] = __builtin_amdgcn_mfma_f32_16x16x32_bf16(ah, bh[n], acc[n], 0, 0, 0);
            acc[n] = __builtin_amdgcn_mfma_f32_16x16x32_bf16(ah, bl[n], acc[n], 0, 0, 0);
            acc[n] = __builtin_amdgcn_mfma_f32_16x16x32_bf16(al, bh[n], acc[n], 0, 0, 0);
        }
    }
}

// Single-stream with register A (layer 1).
template<int NT_TILES, int KSTEPS>
__device__ __forceinline__ void mfma_layer_regA(const bf16x8* ah, const bf16x8* al,
                                                const short* __restrict__ Bhi,
                                                const short* __restrict__ Blo,
                                                int lane, f32x4* acc) {
#pragma unroll
    for (int ks = 0; ks < KSTEPS; ++ks) {
        bf16x8 bh[NT_TILES], bl[NT_TILES];
#pragma unroll
        for (int n = 0; n < NT_TILES; ++n) {
            int f = n * KSTEPS + ks;
            bh[n] = *(const bf16x8*)(Bhi + (((size_t)f * 64 + lane) << 3));
            bl[n] = *(const bf16x8*)(Blo + (((size_t)f * 64 + lane) << 3));
        }
#pragma unroll
        for (int n = 0; n < NT_TILES; ++n) {
            acc[n] = __builtin_amdgcn_mfma_f32_16x16x32_bf16(ah[ks], bh[n], acc[n], 0, 0, 0);
            acc[n] = __builtin_amdgcn_mfma_f32_16x16x32_bf16(ah[ks], bl[n], acc[n], 0, 0, 0);
            acc[n] = __builtin_amdgcn_mfma_f32_16x16x32_bf16(al[ks], bh[n], acc[n], 0, 0, 0);
        }
    }
}

// bias + relu + store C strip to LDS fp32 (C/D layout: col=lane&15, row=(lane>>4)*4+reg)
template<int NT_TILES>
__device__ __forceinline__ void store_C_lds(const f32x4* acc, const float* __restrict__ bias,
                                            float* Ld, int ld, int lane) {
    int r0 = (lane >> 4) << 2;
#pragma unroll
    for (int n = 0; n < NT_TILES; ++n) {
        int col = n * 16 + (lane & 15);
        float bv = bias[col];
#pragma unroll
        for (int q = 0; q < 4; ++q)
            Ld[(r0 + q) * ld + col] = fmaxf(acc[n][q] + bv, 0.f);
    }
}

// ---------------- CSR build ----------------

__global__ __launch_bounds__(256) void k_count(const int* __restrict__ dst, int* __restrict__ cnt, int E) {
    int e = blockIdx.x * 256 + threadIdx.x;
    if (e < E) atomicAdd(&cnt[dst[e]], 1);
}

__global__ __launch_bounds__(256) void k_blocksum(const int* __restrict__ cnt,
                                                  int* __restrict__ bsum, int N) {
    __shared__ int red[256];
    int i = blockIdx.x * 256 + threadIdx.x;
    red[threadIdx.x] = (i < N) ? cnt[i] : 0;
    __syncthreads();
    for (int off = 128; off > 0; off >>= 1) {
        if (threadIdx.x < off) red[threadIdx.x] += red[threadIdx.x + off];
        __syncthreads();
    }
    if (threadIdx.x == 0) bsum[blockIdx.x] = red[0];
}

__global__ __launch_bounds__(1024) void k_scan_bsums(int* __restrict__ bsum, int G) {
    __shared__ int s[1024];
    int t = threadIdx.x;
    int v = (t < G) ? bsum[t] : 0;
    s[t] = v;
    __syncthreads();
    for (int off = 1; off < 1024; off <<= 1) {
        int u = (t >= off) ? s[t - off] : 0;
        __syncthreads();
        s[t] += u;
        __syncthreads();
    }
    if (t < G) bsum[t] = s[t] - v;   // exclusive
}

__global__ __launch_bounds__(256) void k_scan_offs(const int* __restrict__ cnt,
                                                   const int* __restrict__ bsum,
                                                   int* __restrict__ offs,
                                                   int* __restrict__ cursor, int N) {
    __shared__ int s[256];
    int t = threadIdx.x;
    int i = blockIdx.x * 256 + t;
    int v = (i < N) ? cnt[i] : 0;
    s[t] = v;
    __syncthreads();
    for (int off = 1; off < 256; off <<= 1) {
        int u = (t >= off) ? s[t - off] : 0;
        __syncthreads();
        s[t] += u;
        __syncthreads();
    }
    if (i < N) {
        int e = s[t] - v + bsum[blockIdx.x];
        offs[i] = e;
        cursor[i] = e;
    }
}

__global__ __launch_bounds__(256) void k_fill(const int* __restrict__ src, const int* __restrict__ dst,
                                              const int* __restrict__ etype, int* __restrict__ cursor,
                                              int* __restrict__ eidx, int E) {
    int e = blockIdx.x * 256 + threadIdx.x;
    if (e < E) {
        int d = dst[e];
        int p = atomicAdd(&cursor[d], 1);
        eidx[p] = src[e] * 4 + etype[e];
    }
}

// ---------------- Weight prep: split + frag-swizzle all B matrices ----------------

__global__ __launch_bounds__(256) void k_wprep(
    const float* __restrict__ W1, const float* __restrict__ W2,
    const float* __restrict__ W3, const float* __restrict__ Wu1,
    const float* __restrict__ Wu2, const float* __restrict__ Wu3,
    short* __restrict__ Phi, short* __restrict__ Plo)
{
    int pair = blockIdx.x;
    const float* src; int KS, NTl, fragbase, ncol;
    if (pair < 16) {
        int r = pair >> 2, mat = pair & 3;
        if (mat == 0)      { src = W1  + (size_t)r * (D * H);       KS = 4; NTl = 4; fragbase = r * PREL + 0;  ncol = 64;  }
        else if (mat == 1) { src = W2  + (size_t)r * (H * H);       KS = 2; NTl = 4; fragbase = r * PREL + 16; ncol = 64;  }
        else if (mat == 2) { src = W3  + (size_t)r * (H * D);       KS = 2; NTl = 8; fragbase = r * PREL + 24; ncol = 128; }
        else               { src = Wu1 + (size_t)(r + 1) * D * H;   KS = 4; NTl = 4; fragbase = r * PREL + 40; ncol = 64;  }
    } else {
        int mat = pair - 16;
        if (mat == 0)      { src = Wu1; KS = 4; NTl = 4; fragbase = UBASE + 0;  ncol = 64;  }  // rows 0..127
        else if (mat == 1) { src = Wu2; KS = 2; NTl = 4; fragbase = UBASE + 16; ncol = 64;  }
        else               { src = Wu3; KS = 2; NTl = 8; fragbase = UBASE + 24; ncol = 128; }
    }
    int nf = NTl * KS;
    for (int u = threadIdx.x; u < nf * 64; u += 256) {
        int f = u >> 6, lane = u & 63;
        int n = f / KS, ks = f - n * KS;
        int col = n * 16 + (lane & 15);
        int k0 = ks * 32 + ((lane >> 4) << 3);
        size_t dstp = (((size_t)(fragbase + f)) * 64 + (size_t)lane) * 8;
#pragma unroll
        for (int i = 0; i < 8; ++i) {
            short h, l;
            split1(src[(size_t)(k0 + i) * ncol + col], h, l);
            Phi[dstp + i] = h;
            Plo[dstp + i] = l;
        }
    }
}

// ---------------- Stage A: per-(tile, relation) message MLP + Wu1 fold ----------------
// RELATION-MAJOR grid: r = blockIdx.x / tiles, so temporally co-resident blocks
// share one relation's 114 KB B-fragment set (per-ks working set 8 KB -> L1
// hits across near-lockstep waves). Each wave owns 16 rows; X staged direct
// from global into register A-fragments; H1/H2/T share one per-wave 16x132
// LDS strip. Barrier-free. 33792 B LDS => 4 blocks/CU.

__global__ __launch_bounds__(256) void k_mlp_rel(
    const float* __restrict__ X,
    const float* __restrict__ b1, const float* __restrict__ b2, const float* __restrict__ b3,
    const short* __restrict__ Phi, const short* __restrict__ Plo,
    float* __restrict__ U, int N, int tiles)
{
    __shared__ float Bsh[NT * LDC];   // per-wave 16-row strips

    const int tid = threadIdx.x;
    const int lane = tid & 63;
    const int w = tid >> 6;
    const int m16 = w * 16;
    const int r = blockIdx.x / tiles;          // relation-major
    const int n0 = (blockIdx.x - r * tiles) * NT;

    const short* PH = Phi + (size_t)(r * PREL) * PFRAG;
    const short* PL = Plo + (size_t)(r * PREL) * PFRAG;
    const float* b1r = b1 + r * H;
    const float* b2r = b2 + r * H;
    const float* b3r = b3 + r * D;

    float* Ws = &Bsh[m16 * LDC];   // this wave's strip

    // stage X A-fragments direct from global into registers, split once
    bf16x8 ahx[4], alx[4];
    {
        int row = n0 + m16 + (lane & 15);
        const float* xp = X + (size_t)row * D + ((lane >> 4) << 3);
        bool ok = (row < N);
#pragma unroll
        for (int ks = 0; ks < 4; ++ks) {
            float x8[8];
            if (ok) {
                *(float4*)&x8[0] = *(const float4*)(xp + ks * 32);
                *(float4*)&x8[4] = *(const float4*)(xp + ks * 32 + 4);
            } else {
#pragma unroll
                for (int i = 0; i < 8; ++i) x8[i] = 0.f;
            }
            split8(x8, ahx[ks], alx[ks]);
        }
    }

    // layer 1: X(16x128) @ W1(128x64) — A from registers
    f32x4 acc[8];
#pragma unroll
    for (int n = 0; n < 4; ++n) acc[n] = (f32x4){0.f, 0.f, 0.f, 0.f};
    mfma_layer_regA<4, 4>(ahx, alx, PH, PL, lane, acc);
    store_C_lds<4>(acc, b1r, Ws, LDC, lane);   // H1 in cols 0:63

    // layer 2: H1(16x64) @ W2(64x64) -> H2 (in place, cols 0:63)
#pragma unroll
    for (int n = 0; n < 4; ++n) acc[n] = (f32x4){0.f, 0.f, 0.f, 0.f};
    mfma_layer<4, 2>(Ws, LDC, PH + (size_t)16 * PFRAG, PL + (size_t)16 * PFRAG, lane, acc);
    store_C_lds<4>(acc, b2r, Ws, LDC, lane);   // H2

    // layer 3: H2(16x64) @ W3(64x128), relu -> T (cols 0:127, same strip)
#pragma unroll
    for (int n = 0; n < 8; ++n) acc[n] = (f32x4){0.f, 0.f, 0.f, 0.f};
    mfma_layer<8, 2>(Ws, LDC, PH + (size_t)24 * PFRAG, PL + (size_t)24 * PFRAG, lane, acc);
    store_C_lds<8>(acc, b3r, Ws, LDC, lane);   // T

    // U projection: T(16x128) @ Wu1_{r+1}(128x64)
#pragma unroll
    for (int n = 0; n < 4; ++n) acc[n] = (f32x4){0.f, 0.f, 0.f, 0.f};
    mfma_layer<4, 4>(Ws, LDC, PH + (size_t)40 * PFRAG, PL + (size_t)40 * PFRAG, lane, acc);
    {
        int r0 = (lane >> 4) << 2;
#pragma unroll
        for (int n = 0; n < 4; ++n) {
            int col = n * 16 + (lane & 15);
#pragma unroll
            for (int q = 0; q < 4; ++q) {
                int node = n0 + m16 + r0 + q;
                if (node < N)
                    U[((size_t)node * R + r) * H + col] = acc[n][q];
            }
        }
    }
}

// ---------------- Stage B: gather S[n] = sum over in-edges of U[src*4+rel] ----------------

__global__ __launch_bounds__(256) void k_gather(
    const float* __restrict__ U,
    const int* __restrict__ cnt, const int* __restrict__ offs, const int* __restrict__ eidx,
    float* __restrict__ S, int N)
{
    const int wid = threadIdx.x >> 6, lane = threadIdx.x & 63;
    const int n = blockIdx.x * 4 + wid;
    if (n >= N) return;
    const int g = cnt[n];
    const int s = offs[n];
    float acc = 0.f;
    for (int base = 0; base < g; base += 64) {
        int m = g - base; if (m > 64) m = 64;
        int v = 0;
        if (lane < m) v = eidx[s + base + lane];
        for (int j0 = 0; j0 < m; j0 += 8) {
            int lim = m - j0; if (lim > 8) lim = 8;
            float t[8];
#pragma unroll
            for (int j = 0; j < 8; ++j) {
                int vi = __shfl(v, j0 + j);
                t[j] = (j < lim) ? U[(size_t)vi * H + lane] : 0.f;
            }
#pragma unroll
            for (int j = 0; j < 8; ++j) acc += t[j];
        }
    }
    S[(size_t)n * H + lane] = acc;
}

// ---------------- Stage C: updater MLP + select (split-bf16 MFMA, barrier-free) ----------------

__global__ __launch_bounds__(256) void k_upd(
    const float* __restrict__ X, const float* __restrict__ S,
    const int* __restrict__ cnt, const int* __restrict__ node_type,
    const short* __restrict__ Phi, const short* __restrict__ Plo,
    const float* __restrict__ bu1, const float* __restrict__ bu2, const float* __restrict__ bu3,
    float* __restrict__ out, int N)
{
    __shared__ float Hsh[NT * LDC];   // per-wave strips (H1/H2)

    const int tid = threadIdx.x;
    const int lane = tid & 63;
    const int w = tid >> 6;
    const int m16 = w * 16;
    const int n0 = blockIdx.x * NT;

    const short* PH = Phi + (size_t)UBASE * PFRAG;
    const short* PL = Plo + (size_t)UBASE * PFRAG;

    float* Ws = &Hsh[m16 * LDC];

    // stage chunk0 = relu(x) * (indeg > 0) direct into register A-fragments
    bf16x8 ahx[4], alx[4];
    {
        int row = n0 + m16 + (lane & 15);
        bool ok = (row < N) && (cnt[row] > 0);
        const float* xp = X + (size_t)row * D + ((lane >> 4) << 3);
#pragma unroll
        for (int ks = 0; ks < 4; ++ks) {
            float x8[8];
            if (ok) {
                float4 a = *(const float4*)(xp + ks * 32);
                float4 b = *(const float4*)(xp + ks * 32 + 4);
                a = relu4(a); b = relu4(b);
                *(float4*)&x8[0] = a;
                *(float4*)&x8[4] = b;
            } else {
#pragma unroll
                for (int i = 0; i < 8; ++i) x8[i] = 0.f;
            }
            split8(x8, ahx[ks], alx[ks]);
        }
    }

    // layer 1: chunk0 @ Wu1[0:128] + S + bu1, relu -> H1
    f32x4 acc[8];
#pragma unroll
    for (int n = 0; n < 4; ++n) acc[n] = (f32x4){0.f, 0.f, 0.f, 0.f};
    mfma_layer_regA<4, 4>(ahx, alx, PH, PL, lane, acc);
    {
        int r0 = (lane >> 4) << 2;
#pragma unroll
        for (int n = 0; n < 4; ++n) {
            int col = n * 16 + (lane & 15);
            float bv = bu1[col];
#pragma unroll
            for (int q = 0; q < 4; ++q) {
                int node = n0 + m16 + r0 + q;
                float sv = (node < N) ? S[(size_t)node * H + col] : 0.f;
                Ws[(r0 + q) * LDC + col] = fmaxf(acc[n][q] + bv + sv, 0.f);
            }
        }
    }

    // layer 2: H1 @ Wu2, relu -> H2 (in place)
#pragma unroll
    for (int n = 0; n < 4; ++n) acc[n] = (f32x4){0.f, 0.f, 0.f, 0.f};
    mfma_layer<4, 2>(Ws, LDC, PH + (size_t)16 * PFRAG, PL + (size_t)16 * PFRAG, lane, acc);
    store_C_lds<4>(acc, bu2, Ws, LDC, lane);

    // layer 3: H2 @ Wu3 (linear) + select by node_type
#pragma unroll
    for (int n = 0; n < 8; ++n) acc[n] = (f32x4){0.f, 0.f, 0.f, 0.f};
    mfma_layer<8, 2>(Ws, LDC, PH + (size_t)24 * PFRAG, PL + (size_t)24 * PFRAG, lane, acc);
    {
        int r0 = (lane >> 4) << 2;
#pragma unroll
        for (int q = 0; q < 4; ++q) {
            int node = n0 + m16 + r0 + q;
            if (node >= N) continue;
            int t = node_type[node];
#pragma unroll
            for (int n = 0; n < 8; ++n) {
                int col = n * 16 + (lane & 15);
                float o = (t <= 1) ? (acc[n][q] + bu3[col])
                                   : X[(size_t)node * D + col];
                out[(size_t)node * D + col] = o;
            }
        }
    }
}

extern "C" void kernel_launch(void* const* d_in, const int* in_sizes, int n_in,
                              void* d_out, int out_size, void* d_ws, size_t ws_size,
                              hipStream_t stream) {
    const float* X     = (const float*)d_in[0];
    const int*   src   = (const int*)d_in[1];
    const int*   dst   = (const int*)d_in[2];
    const int*   etype = (const int*)d_in[3];
    const int*   ntype = (const int*)d_in[4];
    const float* W1    = (const float*)d_in[5];
    const float* b1    = (const float*)d_in[6];
    const float* W2    = (const float*)d_in[7];
    const float* b2    = (const float*)d_in[8];
    const float* W3    = (const float*)d_in[9];
    const float* b3    = (const float*)d_in[10];
    const float* Wu1   = (const float*)d_in[11];
    const float* bu1   = (const float*)d_in[12];
    const float* Wu2   = (const float*)d_in[13];
    const float* bu2   = (const float*)d_in[14];
    const float* Wu3   = (const float*)d_in[15];
    const float* bu3   = (const float*)d_in[16];
    float* out = (float*)d_out;

    const int N = in_sizes[4];
    const int E = in_sizes[1];

    // workspace layout
    float* U    = (float*)d_ws;                       // N*R*H floats (51.2 MB)
    float* S    = U + (size_t)N * R * H;              // N*H floats (12.8 MB)
    int* cnt    = (int*)(S + (size_t)N * H);          // N
    int* offs   = cnt + N;                            // N
    int* cursor = offs + N;                           // N
    int* eidx   = cursor + N;                         // E
    short* Phi  = (short*)(eidx + E);                 // NFRAG*PFRAG shorts
    short* Plo  = Phi + (size_t)NFRAG * PFRAG;
    int* bsum   = (int*)(Plo + (size_t)NFRAG * PFRAG);  // ceil(N/256)

    hipMemsetAsync(cnt, 0, (size_t)N * sizeof(int), stream);

    int eb = (E + 255) / 256;
    int G = (N + 255) / 256;
    k_count<<<eb, 256, 0, stream>>>(dst, cnt, E);
    k_blocksum<<<G, 256, 0, stream>>>(cnt, bsum, N);
    k_scan_bsums<<<1, 1024, 0, stream>>>(bsum, G);
    k_scan_offs<<<G, 256, 0, stream>>>(cnt, bsum, offs, cursor, N);
    k_fill<<<eb, 256, 0, stream>>>(src, dst, etype, cursor, eidx, E);
    k_wprep<<<19, 256, 0, stream>>>(W1, W2, W3, Wu1, Wu2, Wu3, Phi, Plo);

    int tiles = (N + NT - 1) / NT;
    k_mlp_rel<<<tiles * R, 256, 0, stream>>>(X, b1, b2, b3, Phi, Plo, U, N, tiles);
    k_gather<<<(N + 3) / 4, 256, 0, stream>>>(U, cnt, offs, eidx, S, N);
    k_upd<<<tiles, 256, 0, stream>>>(X, S, cnt, ntype, Phi, Plo, bu1, bu2, bu3, out, N);
}

// Round 12
// 229.801 us; speedup vs baseline: 1.1692x; 1.0585x over previous
//
#include <hip/hip_runtime.h>
#include <hip/hip_bf16.h>

// Problem constants (static per reference)
#define D 128
#define H 64
#define R 4
#define NT 64      // nodes per tile/block (4 waves x 16 rows)
#define LDC 132    // LDS stride (floats) for the per-wave strip

// MFMA fragment types
typedef __attribute__((ext_vector_type(8))) short bf16x8;
typedef __attribute__((ext_vector_type(4))) float f32x4;

// Weight-prep layout: per relation, 56 frags of 512 bf16 elems (64 lanes x 8):
//   W1 frags [0,16), W2 [16,24), W3 [24,40), Wu1_{r+1} [40,56)
// Updater block appended at UBASE: Wu1[0:128] [0,16), Wu2 [16,24), Wu3 [24,40)
// Frag f = ntile*KSTEPS + kstep; lane l covers col = ntile*16+(l&15),
// k = kstep*32 + (l>>4)*8 + i.  (Same phi used for A -> phi cancels.)
#define PREL 56
#define PFRAG 512
#define UBASE (R * PREL)     // 224
#define UPREL 40
#define NFRAG (UBASE + UPREL)

__device__ __forceinline__ float4 relu4(float4 v) {
    return make_float4(fmaxf(v.x, 0.f), fmaxf(v.y, 0.f), fmaxf(v.z, 0.f), fmaxf(v.w, 0.f));
}

// split fp32 -> bf16 hi (RTZ) + bf16 lo (residual, RTZ)
__device__ __forceinline__ void split1(float x, short& hi, short& lo) {
    unsigned u = __float_as_uint(x);
    unsigned hb = u & 0xffff0000u;
    float res = x - __uint_as_float(hb);
    hi = (short)(u >> 16);
    lo = (short)(__float_as_uint(res) >> 16);
}

__device__ __forceinline__ void split8(const float* x8, bf16x8& hi, bf16x8& lo) {
#pragma unroll
    for (int i = 0; i < 8; ++i) {
        short h, l;
        split1(x8[i], h, l);
        hi[i] = h; lo[i] = l;
    }
}

__device__ __forceinline__ void load_split_A(const float* ap, bf16x8& ah, bf16x8& al) {
    float x8[8];
    *(float4*)&x8[0] = *(const float4*)ap;
    *(float4*)&x8[4] = *(const float4*)(ap + 4);
    split8(x8, ah, al);
}

// Single-stream: A from LDS fp32 (split on the fly), B pre-split global, batched loads.
template<int NT_TILES, int KSTEPS>
__device__ __forceinline__ void mfma_layer(const float* Als, int ld,
                                           const short* __restrict__ Bhi,
                                           const short* __restrict__ Blo,
                                           int lane, f32x4* acc) {
#pragma unroll
    for (int ks = 0; ks < KSTEPS; ++ks) {
        bf16x8 ah, al;
        load_split_A(Als + (lane & 15) * ld + ks * 32 + ((lane >> 4) << 3), ah, al);
        bf16x8 bh[NT_TILES], bl[NT_TILES];
#pragma unroll
        for (int n = 0; n < NT_TILES; ++n) {
            int f = n * KSTEPS + ks;
            bh[n] = *(const bf16x8*)(Bhi + (((size_t)f * 64 + lane) << 3));
            bl[n] = *(const bf16x8*)(Blo + (((size_t)f * 64 + lane) << 3));
        }
#pragma unroll
        for (int n = 0; n < NT_TILES; ++n) {
            acc[n] = __builtin_amdgcn_mfma_f32_16x16x32_bf16(ah, bh[n], acc[n], 0, 0, 0);
            acc[n] = __builtin_amdgcn_mfma_f32_16x16x32_bf16(ah, bl[n], acc[n], 0, 0, 0);
            acc[n] = __builtin_amdgcn_mfma_f32_16x16x32_bf16(al, bh[n], acc[n], 0, 0, 0);
        }
    }
}

// Single-stream with register A (layer 1).
template<int NT_TILES, int KSTEPS>
__device__ __forceinline__ void mfma_layer_regA(const bf16x8* ah, const bf16x8* al,
                                                const short* __restrict__ Bhi,
                                                const short* __restrict__ Blo,
                                                int lane, f32x4* acc) {
#pragma unroll
    for (int ks = 0; ks < KSTEPS; ++ks) {
        bf16x8 bh[NT_TILES], bl[NT_TILES];
#pragma unroll
        for (int n = 0; n < NT_TILES; ++n) {
            int f = n * KSTEPS + ks;
            bh[n] = *(const bf16x8*)(Bhi + (((size_t)f * 64 + lane) << 3));
            bl[n] = *(const bf16x8*)(Blo + (((size_t)f * 64 + lane) << 3));
        }
#pragma unroll
        for (int n = 0; n < NT_TILES; ++n) {
            acc[n] = __builtin_amdgcn_mfma_f32_16x16x32_bf16(ah[ks], bh[n], acc[n], 0, 0, 0);
            acc[n] = __builtin_amdgcn_mfma_f32_16x16x32_bf16(ah[ks], bl[n], acc[n], 0, 0, 0);
            acc[n] = __builtin_amdgcn_mfma_f32_16x16x32_bf16(al[ks], bh[n], acc[n], 0, 0, 0);
        }
    }
}

// bias + relu + store C strip to LDS fp32 (C/D layout: col=lane&15, row=(lane>>4)*4+reg)
template<int NT_TILES>
__device__ __forceinline__ void store_C_lds(const f32x4* acc, const float* __restrict__ bias,
                                            float* Ld, int ld, int lane) {
    int r0 = (lane >> 4) << 2;
#pragma unroll
    for (int n = 0; n < NT_TILES; ++n) {
        int col = n * 16 + (lane & 15);
        float bv = bias[col];
#pragma unroll
        for (int q = 0; q < 4; ++q)
            Ld[(r0 + q) * ld + col] = fmaxf(acc[n][q] + bv, 0.f);
    }
}

// ---------------- CSR build ----------------

__global__ __launch_bounds__(256) void k_count(const int* __restrict__ dst, int* __restrict__ cnt, int E) {
    int e = blockIdx.x * 256 + threadIdx.x;
    if (e < E) atomicAdd(&cnt[dst[e]], 1);
}

__global__ __launch_bounds__(256) void k_blocksum(const int* __restrict__ cnt,
                                                  int* __restrict__ bsum, int N) {
    __shared__ int red[256];
    int i = blockIdx.x * 256 + threadIdx.x;
    red[threadIdx.x] = (i < N) ? cnt[i] : 0;
    __syncthreads();
    for (int off = 128; off > 0; off >>= 1) {
        if (threadIdx.x < off) red[threadIdx.x] += red[threadIdx.x + off];
        __syncthreads();
    }
    if (threadIdx.x == 0) bsum[blockIdx.x] = red[0];
}

__global__ __launch_bounds__(1024) void k_scan_bsums(int* __restrict__ bsum, int G) {
    __shared__ int s[1024];
    int t = threadIdx.x;
    int v = (t < G) ? bsum[t] : 0;
    s[t] = v;
    __syncthreads();
    for (int off = 1; off < 1024; off <<= 1) {
        int u = (t >= off) ? s[t - off] : 0;
        __syncthreads();
        s[t] += u;
        __syncthreads();
    }
    if (t < G) bsum[t] = s[t] - v;   // exclusive
}

__global__ __launch_bounds__(256) void k_scan_offs(const int* __restrict__ cnt,
                                                   const int* __restrict__ bsum,
                                                   int* __restrict__ offs,
                                                   int* __restrict__ cursor, int N) {
    __shared__ int s[256];
    int t = threadIdx.x;
    int i = blockIdx.x * 256 + t;
    int v = (i < N) ? cnt[i] : 0;
    s[t] = v;
    __syncthreads();
    for (int off = 1; off < 256; off <<= 1) {
        int u = (t >= off) ? s[t - off] : 0;
        __syncthreads();
        s[t] += u;
        __syncthreads();
    }
    if (i < N) {
        int e = s[t] - v + bsum[blockIdx.x];
        offs[i] = e;
        cursor[i] = e;
    }
}

__global__ __launch_bounds__(256) void k_fill(const int* __restrict__ src, const int* __restrict__ dst,
                                              const int* __restrict__ etype, int* __restrict__ cursor,
                                              int* __restrict__ eidx, int E) {
    int e = blockIdx.x * 256 + threadIdx.x;
    if (e < E) {
        int d = dst[e];
        int p = atomicAdd(&cursor[d], 1);
        eidx[p] = src[e] * 4 + etype[e];
    }
}

// ---------------- Weight prep: split + frag-swizzle all B matrices ----------------

__global__ __launch_bounds__(256) void k_wprep(
    const float* __restrict__ W1, const float* __restrict__ W2,
    const float* __restrict__ W3, const float* __restrict__ Wu1,
    const float* __restrict__ Wu2, const float* __restrict__ Wu3,
    short* __restrict__ Phi, short* __restrict__ Plo)
{
    int pair = blockIdx.x;
    const float* src; int KS, NTl, fragbase, ncol;
    if (pair < 16) {
        int r = pair >> 2, mat = pair & 3;
        if (mat == 0)      { src = W1  + (size_t)r * (D * H);       KS = 4; NTl = 4; fragbase = r * PREL + 0;  ncol = 64;  }
        else if (mat == 1) { src = W2  + (size_t)r * (H * H);       KS = 2; NTl = 4; fragbase = r * PREL + 16; ncol = 64;  }
        else if (mat == 2) { src = W3  + (size_t)r * (H * D);       KS = 2; NTl = 8; fragbase = r * PREL + 24; ncol = 128; }
        else               { src = Wu1 + (size_t)(r + 1) * D * H;   KS = 4; NTl = 4; fragbase = r * PREL + 40; ncol = 64;  }
    } else {
        int mat = pair - 16;
        if (mat == 0)      { src = Wu1; KS = 4; NTl = 4; fragbase = UBASE + 0;  ncol = 64;  }  // rows 0..127
        else if (mat == 1) { src = Wu2; KS = 2; NTl = 4; fragbase = UBASE + 16; ncol = 64;  }
        else               { src = Wu3; KS = 2; NTl = 8; fragbase = UBASE + 24; ncol = 128; }
    }
    int nf = NTl * KS;
    for (int u = threadIdx.x; u < nf * 64; u += 256) {
        int f = u >> 6, lane = u & 63;
        int n = f / KS, ks = f - n * KS;
        int col = n * 16 + (lane & 15);
        int k0 = ks * 32 + ((lane >> 4) << 3);
        size_t dstp = (((size_t)(fragbase + f)) * 64 + (size_t)lane) * 8;
#pragma unroll
        for (int i = 0; i < 8; ++i) {
            short h, l;
            split1(src[(size_t)(k0 + i) * ncol + col], h, l);
            Phi[dstp + i] = h;
            Plo[dstp + i] = l;
        }
    }
}

// ---------------- Stage A: per-(tile, relation) message MLP + Wu1 fold ----------------
// Relation-major grid. Each wave owns 16 rows; X staged direct from global into
// register A-fragments; H1/H2/T share one per-wave 16x132 LDS strip. Barrier-free.
// 33792 B LDS => 4 blocks/CU; __launch_bounds__(256,4) declares exactly that
// occupancy so the allocator can use ~128 VGPRs (B-fragment load pipelining)
// instead of the default-8-waves 64-VGPR budget.

__global__ __launch_bounds__(256, 4) void k_mlp_rel(
    const float* __restrict__ X,
    const float* __restrict__ b1, const float* __restrict__ b2, const float* __restrict__ b3,
    const short* __restrict__ Phi, const short* __restrict__ Plo,
    float* __restrict__ U, int N, int tiles)
{
    __shared__ float Bsh[NT * LDC];   // per-wave 16-row strips

    const int tid = threadIdx.x;
    const int lane = tid & 63;
    const int w = tid >> 6;
    const int m16 = w * 16;
    const int r = blockIdx.x / tiles;          // relation-major
    const int n0 = (blockIdx.x - r * tiles) * NT;

    const short* PH = Phi + (size_t)(r * PREL) * PFRAG;
    const short* PL = Plo + (size_t)(r * PREL) * PFRAG;
    const float* b1r = b1 + r * H;
    const float* b2r = b2 + r * H;
    const float* b3r = b3 + r * D;

    float* Ws = &Bsh[m16 * LDC];   // this wave's strip

    // stage X A-fragments direct from global into registers, split once
    bf16x8 ahx[4], alx[4];
    {
        int row = n0 + m16 + (lane & 15);
        const float* xp = X + (size_t)row * D + ((lane >> 4) << 3);
        bool ok = (row < N);
#pragma unroll
        for (int ks = 0; ks < 4; ++ks) {
            float x8[8];
            if (ok) {
                *(float4*)&x8[0] = *(const float4*)(xp + ks * 32);
                *(float4*)&x8[4] = *(const float4*)(xp + ks * 32 + 4);
            } else {
#pragma unroll
                for (int i = 0; i < 8; ++i) x8[i] = 0.f;
            }
            split8(x8, ahx[ks], alx[ks]);
        }
    }

    // layer 1: X(16x128) @ W1(128x64) — A from registers
    f32x4 acc[8];
#pragma unroll
    for (int n = 0; n < 4; ++n) acc[n] = (f32x4){0.f, 0.f, 0.f, 0.f};
    mfma_layer_regA<4, 4>(ahx, alx, PH, PL, lane, acc);
    store_C_lds<4>(acc, b1r, Ws, LDC, lane);   // H1 in cols 0:63

    // layer 2: H1(16x64) @ W2(64x64) -> H2 (in place, cols 0:63)
#pragma unroll
    for (int n = 0; n < 4; ++n) acc[n] = (f32x4){0.f, 0.f, 0.f, 0.f};
    mfma_layer<4, 2>(Ws, LDC, PH + (size_t)16 * PFRAG, PL + (size_t)16 * PFRAG, lane, acc);
    store_C_lds<4>(acc, b2r, Ws, LDC, lane);   // H2

    // layer 3: H2(16x64) @ W3(64x128), relu -> T (cols 0:127, same strip)
#pragma unroll
    for (int n = 0; n < 8; ++n) acc[n] = (f32x4){0.f, 0.f, 0.f, 0.f};
    mfma_layer<8, 2>(Ws, LDC, PH + (size_t)24 * PFRAG, PL + (size_t)24 * PFRAG, lane, acc);
    store_C_lds<8>(acc, b3r, Ws, LDC, lane);   // T

    // U projection: T(16x128) @ Wu1_{r+1}(128x64)
#pragma unroll
    for (int n = 0; n < 4; ++n) acc[n] = (f32x4){0.f, 0.f, 0.f, 0.f};
    mfma_layer<4, 4>(Ws, LDC, PH + (size_t)40 * PFRAG, PL + (size_t)40 * PFRAG, lane, acc);
    {
        int r0 = (lane >> 4) << 2;
#pragma unroll
        for (int n = 0; n < 4; ++n) {
            int col = n * 16 + (lane & 15);
#pragma unroll
            for (int q = 0; q < 4; ++q) {
                int node = n0 + m16 + r0 + q;
                if (node < N)
                    U[((size_t)node * R + r) * H + col] = acc[n][q];
            }
        }
    }
}

// ---------------- Stage B: gather S[n] = sum over in-edges of U[src*4+rel] ----------------

__global__ __launch_bounds__(256) void k_gather(
    const float* __restrict__ U,
    const int* __restrict__ cnt, const int* __restrict__ offs, const int* __restrict__ eidx,
    float* __restrict__ S, int N)
{
    const int wid = threadIdx.x >> 6, lane = threadIdx.x & 63;
    const int n = blockIdx.x * 4 + wid;
    if (n >= N) return;
    const int g = cnt[n];
    const int s = offs[n];
    float acc = 0.f;
    for (int base = 0; base < g; base += 64) {
        int m = g - base; if (m > 64) m = 64;
        int v = 0;
        if (lane < m) v = eidx[s + base + lane];
        for (int j0 = 0; j0 < m; j0 += 8) {
            int lim = m - j0; if (lim > 8) lim = 8;
            float t[8];
#pragma unroll
            for (int j = 0; j < 8; ++j) {
                int vi = __shfl(v, j0 + j);
                t[j] = (j < lim) ? U[(size_t)vi * H + lane] : 0.f;
            }
#pragma unroll
            for (int j = 0; j < 8; ++j) acc += t[j];
        }
    }
    S[(size_t)n * H + lane] = acc;
}

// ---------------- Stage C: updater MLP + select (split-bf16 MFMA, barrier-free) ----------------

__global__ __launch_bounds__(256, 4) void k_upd(
    const float* __restrict__ X, const float* __restrict__ S,
    const int* __restrict__ cnt, const int* __restrict__ node_type,
    const short* __restrict__ Phi, const short* __restrict__ Plo,
    const float* __restrict__ bu1, const float* __restrict__ bu2, const float* __restrict__ bu3,
    float* __restrict__ out, int N)
{
    __shared__ float Hsh[NT * LDC];   // per-wave strips (H1/H2)

    const int tid = threadIdx.x;
    const int lane = tid & 63;
    const int w = tid >> 6;
    const int m16 = w * 16;
    const int n0 = blockIdx.x * NT;

    const short* PH = Phi + (size_t)UBASE * PFRAG;
    const short* PL = Plo + (size_t)UBASE * PFRAG;

    float* Ws = &Hsh[m16 * LDC];

    // stage chunk0 = relu(x) * (indeg > 0) direct into register A-fragments
    bf16x8 ahx[4], alx[4];
    {
        int row = n0 + m16 + (lane & 15);
        bool ok = (row < N) && (cnt[row] > 0);
        const float* xp = X + (size_t)row * D + ((lane >> 4) << 3);
#pragma unroll
        for (int ks = 0; ks < 4; ++ks) {
            float x8[8];
            if (ok) {
                float4 a = *(const float4*)(xp + ks * 32);
                float4 b = *(const float4*)(xp + ks * 32 + 4);
                a = relu4(a); b = relu4(b);
                *(float4*)&x8[0] = a;
                *(float4*)&x8[4] = b;
            } else {
#pragma unroll
                for (int i = 0; i < 8; ++i) x8[i] = 0.f;
            }
            split8(x8, ahx[ks], alx[ks]);
        }
    }

    // layer 1: chunk0 @ Wu1[0:128] + S + bu1, relu -> H1
    f32x4 acc[8];
#pragma unroll
    for (int n = 0; n < 4; ++n) acc[n] = (f32x4){0.f, 0.f, 0.f, 0.f};
    mfma_layer_regA<4, 4>(ahx, alx, PH, PL, lane, acc);
    {
        int r0 = (lane >> 4) << 2;
#pragma unroll
        for (int n = 0; n < 4; ++n) {
            int col = n * 16 + (lane & 15);
            float bv = bu1[col];
#pragma unroll
            for (int q = 0; q < 4; ++q) {
                int node = n0 + m16 + r0 + q;
                float sv = (node < N) ? S[(size_t)node * H + col] : 0.f;
                Ws[(r0 + q) * LDC + col] = fmaxf(acc[n][q] + bv + sv, 0.f);
            }
        }
    }

    // layer 2: H1 @ Wu2, relu -> H2 (in place)
#pragma unroll
    for (int n = 0; n < 4; ++n) acc[n] = (f32x4){0.f, 0.f, 0.f, 0.f};
    mfma_layer<4, 2>(Ws, LDC, PH + (size_t)16 * PFRAG, PL + (size_t)16 * PFRAG, lane, acc);
    store_C_lds<4>(acc, bu2, Ws, LDC, lane);

    // layer 3: H2 @ Wu3 (linear) + select by node_type
#pragma unroll
    for (int n = 0; n < 8; ++n) acc[n] = (f32x4){0.f, 0.f, 0.f, 0.f};
    mfma_layer<8, 2>(Ws, LDC, PH + (size_t)24 * PFRAG, PL + (size_t)24 * PFRAG, lane, acc);
    {
        int r0 = (lane >> 4) << 2;
#pragma unroll
        for (int q = 0; q < 4; ++q) {
            int node = n0 + m16 + r0 + q;
            if (node >= N) continue;
            int t = node_type[node];
#pragma unroll
            for (int n = 0; n < 8; ++n) {
                int col = n * 16 + (lane & 15);
                float o = (t <= 1) ? (acc[n][q] + bu3[col])
                                   : X[(size_t)node * D + col];
                out[(size_t)node * D + col] = o;
            }
        }
    }
}

extern "C" void kernel_launch(void* const* d_in, const int* in_sizes, int n_in,
                              void* d_out, int out_size, void* d_ws, size_t ws_size,
                              hipStream_t stream) {
    const float* X     = (const float*)d_in[0];
    const int*   src   = (const int*)d_in[1];
    const int*   dst   = (const int*)d_in[2];
    const int*   etype = (const int*)d_in[3];
    const int*   ntype = (const int*)d_in[4];
    const float* W1    = (const float*)d_in[5];
    const float* b1    = (const float*)d_in[6];
    const float* W2    = (const float*)d_in[7];
    const float* b2    = (const float*)d_in[8];
    const float* W3    = (const float*)d_in[9];
    const float* b3    = (const float*)d_in[10];
    const float* Wu1   = (const float*)d_in[11];
    const float* bu1   = (const float*)d_in[12];
    const float* Wu2   = (const float*)d_in[13];
    const float* bu2   = (const float*)d_in[14];
    const float* Wu3   = (const float*)d_in[15];
    const float* bu3   = (const float*)d_in[16];
    float* out = (float*)d_out;

    const int N = in_sizes[4];
    const int E = in_sizes[1];

    // workspace layout
    float* U    = (float*)d_ws;                       // N*R*H floats (51.2 MB)
    float* S    = U + (size_t)N * R * H;              // N*H floats (12.8 MB)
    int* cnt    = (int*)(S + (size_t)N * H);          // N
    int* offs   = cnt + N;                            // N
    int* cursor = offs + N;                           // N
    int* eidx   = cursor + N;                         // E
    short* Phi  = (short*)(eidx + E);                 // NFRAG*PFRAG shorts
    short* Plo  = Phi + (size_t)NFRAG * PFRAG;
    int* bsum   = (int*)(Plo + (size_t)NFRAG * PFRAG);  // ceil(N/256)

    hipMemsetAsync(cnt, 0, (size_t)N * sizeof(int), stream);

    int eb = (E + 255) / 256;
    int G = (N + 255) / 256;
    k_count<<<eb, 256, 0, stream>>>(dst, cnt, E);
    k_blocksum<<<G, 256, 0, stream>>>(cnt, bsum, N);
    k_scan_bsums<<<1, 1024, 0, stream>>>(bsum, G);
    k_scan_offs<<<G, 256, 0, stream>>>(cnt, bsum, offs, cursor, N);
    k_fill<<<eb, 256, 0, stream>>>(src, dst, etype, cursor, eidx, E);
    k_wprep<<<19, 256, 0, stream>>>(W1, W2, W3, Wu1, Wu2, Wu3, Phi, Plo);

    int tiles = (N + NT - 1) / NT;
    k_mlp_rel<<<tiles * R, 256, 0, stream>>>(X, b1, b2, b3, Phi, Plo, U, N, tiles);
    k_gather<<<(N + 3) / 4, 256, 0, stream>>>(U, cnt, offs, eidx, S, N);
    k_upd<<<tiles, 256, 0, stream>>>(X, S, cnt, ntype, Phi, Plo, bu1, bu2, bu3, out, N);
}

// Round 13
// 183.393 us; speedup vs baseline: 1.4651x; 1.2530x over previous
//
#include <hip/hip_runtime.h>
#include <hip/hip_bf16.h>

// Problem constants (static per reference)
#define D 128
#define H 64
#define R 4
#define NT 64      // nodes per tile/block (4 waves x 16 rows)
#define LDC 132    // LDS stride (floats) for the per-wave strip
#define CAP 128    // per-node edge bucket capacity (deg ~ Poisson(16); P(>128) ~ 1e-60)

// MFMA fragment types
typedef __attribute__((ext_vector_type(8))) short bf16x8;
typedef __attribute__((ext_vector_type(4))) float f32x4;

// Weight-prep layout: per relation, 56 frags of 512 bf16 elems (64 lanes x 8):
//   W1 frags [0,16), W2 [16,24), W3 [24,40), Wu1_{r+1} [40,56)
// Updater block appended at UBASE: Wu1[0:128] [0,16), Wu2 [16,24), Wu3 [24,40)
// Frag f = ntile*KSTEPS + kstep; lane l covers col = ntile*16+(l&15),
// k = kstep*32 + (l>>4)*8 + i.  (Same phi used for A -> phi cancels.)
#define PREL 56
#define PFRAG 512
#define UBASE (R * PREL)     // 224
#define UPREL 40
#define NFRAG (UBASE + UPREL)

__device__ __forceinline__ float4 relu4(float4 v) {
    return make_float4(fmaxf(v.x, 0.f), fmaxf(v.y, 0.f), fmaxf(v.z, 0.f), fmaxf(v.w, 0.f));
}

// split fp32 -> bf16 hi (RTZ) + bf16 lo (residual, RTZ)
__device__ __forceinline__ void split1(float x, short& hi, short& lo) {
    unsigned u = __float_as_uint(x);
    unsigned hb = u & 0xffff0000u;
    float res = x - __uint_as_float(hb);
    hi = (short)(u >> 16);
    lo = (short)(__float_as_uint(res) >> 16);
}

__device__ __forceinline__ void split8(const float* x8, bf16x8& hi, bf16x8& lo) {
#pragma unroll
    for (int i = 0; i < 8; ++i) {
        short h, l;
        split1(x8[i], h, l);
        hi[i] = h; lo[i] = l;
    }
}

__device__ __forceinline__ void load_split_A(const float* ap, bf16x8& ah, bf16x8& al) {
    float x8[8];
    *(float4*)&x8[0] = *(const float4*)ap;
    *(float4*)&x8[4] = *(const float4*)(ap + 4);
    split8(x8, ah, al);
}

// Single-stream: A from LDS fp32 (split on the fly), B pre-split global, batched loads.
template<int NT_TILES, int KSTEPS>
__device__ __forceinline__ void mfma_layer(const float* Als, int ld,
                                           const short* __restrict__ Bhi,
                                           const short* __restrict__ Blo,
                                           int lane, f32x4* acc) {
#pragma unroll
    for (int ks = 0; ks < KSTEPS; ++ks) {
        bf16x8 ah, al;
        load_split_A(Als + (lane & 15) * ld + ks * 32 + ((lane >> 4) << 3), ah, al);
        bf16x8 bh[NT_TILES], bl[NT_TILES];
#pragma unroll
        for (int n = 0; n < NT_TILES; ++n) {
            int f = n * KSTEPS + ks;
            bh[n] = *(const bf16x8*)(Bhi + (((size_t)f * 64 + lane) << 3));
            bl[n] = *(const bf16x8*)(Blo + (((size_t)f * 64 + lane) << 3));
        }
#pragma unroll
        for (int n = 0; n < NT_TILES; ++n) {
            acc[n] = __builtin_amdgcn_mfma_f32_16x16x32_bf16(ah, bh[n], acc[n], 0, 0, 0);
            acc[n] = __builtin_amdgcn_mfma_f32_16x16x32_bf16(ah, bl[n], acc[n], 0, 0, 0);
            acc[n] = __builtin_amdgcn_mfma_f32_16x16x32_bf16(al, bh[n], acc[n], 0, 0, 0);
        }
    }
}

// Single-stream with register A (layer 1).
template<int NT_TILES, int KSTEPS>
__device__ __forceinline__ void mfma_layer_regA(const bf16x8* ah, const bf16x8* al,
                                                const short* __restrict__ Bhi,
                                                const short* __restrict__ Blo,
                                                int lane, f32x4* acc) {
#pragma unroll
    for (int ks = 0; ks < KSTEPS; ++ks) {
        bf16x8 bh[NT_TILES], bl[NT_TILES];
#pragma unroll
        for (int n = 0; n < NT_TILES; ++n) {
            int f = n * KSTEPS + ks;
            bh[n] = *(const bf16x8*)(Bhi + (((size_t)f * 64 + lane) << 3));
            bl[n] = *(const bf16x8*)(Blo + (((size_t)f * 64 + lane) << 3));
        }
#pragma unroll
        for (int n = 0; n < NT_TILES; ++n) {
            acc[n] = __builtin_amdgcn_mfma_f32_16x16x32_bf16(ah[ks], bh[n], acc[n], 0, 0, 0);
            acc[n] = __builtin_amdgcn_mfma_f32_16x16x32_bf16(ah[ks], bl[n], acc[n], 0, 0, 0);
            acc[n] = __builtin_amdgcn_mfma_f32_16x16x32_bf16(al[ks], bh[n], acc[n], 0, 0, 0);
        }
    }
}

// bias + relu + store C strip to LDS fp32 (C/D layout: col=lane&15, row=(lane>>4)*4+reg)
template<int NT_TILES>
__device__ __forceinline__ void store_C_lds(const f32x4* acc, const float* __restrict__ bias,
                                            float* Ld, int ld, int lane) {
    int r0 = (lane >> 4) << 2;
#pragma unroll
    for (int n = 0; n < NT_TILES; ++n) {
        int col = n * 16 + (lane & 15);
        float bv = bias[col];
#pragma unroll
        for (int q = 0; q < 4; ++q)
            Ld[(r0 + q) * ld + col] = fmaxf(acc[n][q] + bv, 0.f);
    }
}

// ---------------- Bucketed CSR: one pass does count + fill ----------------

__global__ __launch_bounds__(256) void k_fill(const int* __restrict__ src, const int* __restrict__ dst,
                                              const int* __restrict__ etype, int* __restrict__ cnt,
                                              int* __restrict__ eidx, int E) {
    int e = blockIdx.x * 256 + threadIdx.x;
    if (e < E) {
        int d = dst[e];
        int p = atomicAdd(&cnt[d], 1);
        if (p < CAP) eidx[(size_t)d * CAP + p] = src[e] * 4 + etype[e];
    }
}

// ---------------- Weight prep: split + frag-swizzle all B matrices ----------------

__global__ __launch_bounds__(256) void k_wprep(
    const float* __restrict__ W1, const float* __restrict__ W2,
    const float* __restrict__ W3, const float* __restrict__ Wu1,
    const float* __restrict__ Wu2, const float* __restrict__ Wu3,
    short* __restrict__ Phi, short* __restrict__ Plo)
{
    int pair = blockIdx.x;
    const float* src; int KS, NTl, fragbase, ncol;
    if (pair < 16) {
        int r = pair >> 2, mat = pair & 3;
        if (mat == 0)      { src = W1  + (size_t)r * (D * H);       KS = 4; NTl = 4; fragbase = r * PREL + 0;  ncol = 64;  }
        else if (mat == 1) { src = W2  + (size_t)r * (H * H);       KS = 2; NTl = 4; fragbase = r * PREL + 16; ncol = 64;  }
        else if (mat == 2) { src = W3  + (size_t)r * (H * D);       KS = 2; NTl = 8; fragbase = r * PREL + 24; ncol = 128; }
        else               { src = Wu1 + (size_t)(r + 1) * D * H;   KS = 4; NTl = 4; fragbase = r * PREL + 40; ncol = 64;  }
    } else {
        int mat = pair - 16;
        if (mat == 0)      { src = Wu1; KS = 4; NTl = 4; fragbase = UBASE + 0;  ncol = 64;  }  // rows 0..127
        else if (mat == 1) { src = Wu2; KS = 2; NTl = 4; fragbase = UBASE + 16; ncol = 64;  }
        else               { src = Wu3; KS = 2; NTl = 8; fragbase = UBASE + 24; ncol = 128; }
    }
    int nf = NTl * KS;
    for (int u = threadIdx.x; u < nf * 64; u += 256) {
        int f = u >> 6, lane = u & 63;
        int n = f / KS, ks = f - n * KS;
        int col = n * 16 + (lane & 15);
        int k0 = ks * 32 + ((lane >> 4) << 3);
        size_t dstp = (((size_t)(fragbase + f)) * 64 + (size_t)lane) * 8;
#pragma unroll
        for (int i = 0; i < 8; ++i) {
            short h, l;
            split1(src[(size_t)(k0 + i) * ncol + col], h, l);
            Phi[dstp + i] = h;
            Plo[dstp + i] = l;
        }
    }
}

// ---------------- Stage A: per-(tile, relation) message MLP + Wu1 fold ----------------
// Relation-major grid. Each wave owns 16 rows; X staged direct from global into
// register A-fragments; H1/H2/T share one per-wave 16x132 LDS strip. Barrier-free.

__global__ __launch_bounds__(256, 4) void k_mlp_rel(
    const float* __restrict__ X,
    const float* __restrict__ b1, const float* __restrict__ b2, const float* __restrict__ b3,
    const short* __restrict__ Phi, const short* __restrict__ Plo,
    float* __restrict__ U, int N, int tiles)
{
    __shared__ float Bsh[NT * LDC];   // per-wave 16-row strips

    const int tid = threadIdx.x;
    const int lane = tid & 63;
    const int w = tid >> 6;
    const int m16 = w * 16;
    const int r = blockIdx.x / tiles;          // relation-major
    const int n0 = (blockIdx.x - r * tiles) * NT;

    const short* PH = Phi + (size_t)(r * PREL) * PFRAG;
    const short* PL = Plo + (size_t)(r * PREL) * PFRAG;
    const float* b1r = b1 + r * H;
    const float* b2r = b2 + r * H;
    const float* b3r = b3 + r * D;

    float* Ws = &Bsh[m16 * LDC];   // this wave's strip

    // stage X A-fragments direct from global into registers, split once
    bf16x8 ahx[4], alx[4];
    {
        int row = n0 + m16 + (lane & 15);
        const float* xp = X + (size_t)row * D + ((lane >> 4) << 3);
        bool ok = (row < N);
#pragma unroll
        for (int ks = 0; ks < 4; ++ks) {
            float x8[8];
            if (ok) {
                *(float4*)&x8[0] = *(const float4*)(xp + ks * 32);
                *(float4*)&x8[4] = *(const float4*)(xp + ks * 32 + 4);
            } else {
#pragma unroll
                for (int i = 0; i < 8; ++i) x8[i] = 0.f;
            }
            split8(x8, ahx[ks], alx[ks]);
        }
    }

    // layer 1: X(16x128) @ W1(128x64) — A from registers
    f32x4 acc[8];
#pragma unroll
    for (int n = 0; n < 4; ++n) acc[n] = (f32x4){0.f, 0.f, 0.f, 0.f};
    mfma_layer_regA<4, 4>(ahx, alx, PH, PL, lane, acc);
    store_C_lds<4>(acc, b1r, Ws, LDC, lane);   // H1 in cols 0:63

    // layer 2: H1(16x64) @ W2(64x64) -> H2 (in place, cols 0:63)
#pragma unroll
    for (int n = 0; n < 4; ++n) acc[n] = (f32x4){0.f, 0.f, 0.f, 0.f};
    mfma_layer<4, 2>(Ws, LDC, PH + (size_t)16 * PFRAG, PL + (size_t)16 * PFRAG, lane, acc);
    store_C_lds<4>(acc, b2r, Ws, LDC, lane);   // H2

    // layer 3: H2(16x64) @ W3(64x128), relu -> T (cols 0:127, same strip)
#pragma unroll
    for (int n = 0; n < 8; ++n) acc[n] = (f32x4){0.f, 0.f, 0.f, 0.f};
    mfma_layer<8, 2>(Ws, LDC, PH + (size_t)24 * PFRAG, PL + (size_t)24 * PFRAG, lane, acc);
    store_C_lds<8>(acc, b3r, Ws, LDC, lane);   // T

    // U projection: T(16x128) @ Wu1_{r+1}(128x64)
#pragma unroll
    for (int n = 0; n < 4; ++n) acc[n] = (f32x4){0.f, 0.f, 0.f, 0.f};
    mfma_layer<4, 4>(Ws, LDC, PH + (size_t)40 * PFRAG, PL + (size_t)40 * PFRAG, lane, acc);
    {
        int r0 = (lane >> 4) << 2;
#pragma unroll
        for (int n = 0; n < 4; ++n) {
            int col = n * 16 + (lane & 15);
#pragma unroll
            for (int q = 0; q < 4; ++q) {
                int node = n0 + m16 + r0 + q;
                if (node < N)
                    U[((size_t)node * R + r) * H + col] = acc[n][q];
            }
        }
    }
}

// ---------------- Stage B: gather S[n] = sum over in-edges of U[src*4+rel] ----------------
// One wave per node; lanes load float2 (32 lanes cover a 64-float U row), so
// each 8-deep in-flight batch covers 16 edges; halves merged via shfl_xor(32).

__global__ __launch_bounds__(256) void k_gather(
    const float* __restrict__ U,
    const int* __restrict__ cnt, const int* __restrict__ eidx,
    float* __restrict__ S, int N)
{
    const int wid = threadIdx.x >> 6, lane = threadIdx.x & 63;
    const int n = blockIdx.x * 4 + wid;
    if (n >= N) return;
    int g = cnt[n]; if (g > CAP) g = CAP;
    const int* ep = eidx + (size_t)n * CAP;
    const int half = lane >> 5;      // which edge of each pair
    const int c2 = lane & 31;        // float2 column index
    float ax = 0.f, ay = 0.f;
    for (int base = 0; base < g; base += 64) {
        int m = g - base; if (m > 64) m = 64;
        int v = 0;
        if (lane < m) v = ep[base + lane];
        for (int j0 = 0; j0 < m; j0 += 16) {
            int lim = m - j0; if (lim > 16) lim = 16;
            float2 t[8];
#pragma unroll
            for (int p = 0; p < 8; ++p) {
                int vi = __shfl(v, j0 + 2 * p + half);        // broadcast edge idx
                bool ok = (2 * p + half) < lim;
                t[p] = ok ? *(const float2*)&U[(size_t)vi * H + (c2 << 1)]
                          : make_float2(0.f, 0.f);            // 16 edges in flight/wave
            }
#pragma unroll
            for (int p = 0; p < 8; ++p) { ax += t[p].x; ay += t[p].y; }
        }
    }
    ax += __shfl_xor(ax, 32);
    ay += __shfl_xor(ay, 32);
    if (half == 0)
        *(float2*)&S[(size_t)n * H + (c2 << 1)] = make_float2(ax, ay);
}

// ---------------- Stage C: updater MLP + select (split-bf16 MFMA, barrier-free) ----------------

__global__ __launch_bounds__(256, 4) void k_upd(
    const float* __restrict__ X, const float* __restrict__ S,
    const int* __restrict__ cnt, const int* __restrict__ node_type,
    const short* __restrict__ Phi, const short* __restrict__ Plo,
    const float* __restrict__ bu1, const float* __restrict__ bu2, const float* __restrict__ bu3,
    float* __restrict__ out, int N)
{
    __shared__ float Hsh[NT * LDC];   // per-wave strips (H1/H2)

    const int tid = threadIdx.x;
    const int lane = tid & 63;
    const int w = tid >> 6;
    const int m16 = w * 16;
    const int n0 = blockIdx.x * NT;

    const short* PH = Phi + (size_t)UBASE * PFRAG;
    const short* PL = Plo + (size_t)UBASE * PFRAG;

    float* Ws = &Hsh[m16 * LDC];

    // stage chunk0 = relu(x) * (indeg > 0) direct into register A-fragments
    bf16x8 ahx[4], alx[4];
    {
        int row = n0 + m16 + (lane & 15);
        bool ok = (row < N) && (cnt[row] > 0);
        const float* xp = X + (size_t)row * D + ((lane >> 4) << 3);
#pragma unroll
        for (int ks = 0; ks < 4; ++ks) {
            float x8[8];
            if (ok) {
                float4 a = *(const float4*)(xp + ks * 32);
                float4 b = *(const float4*)(xp + ks * 32 + 4);
                a = relu4(a); b = relu4(b);
                *(float4*)&x8[0] = a;
                *(float4*)&x8[4] = b;
            } else {
#pragma unroll
                for (int i = 0; i < 8; ++i) x8[i] = 0.f;
            }
            split8(x8, ahx[ks], alx[ks]);
        }
    }

    // layer 1: chunk0 @ Wu1[0:128] + S + bu1, relu -> H1
    f32x4 acc[8];
#pragma unroll
    for (int n = 0; n < 4; ++n) acc[n] = (f32x4){0.f, 0.f, 0.f, 0.f};
    mfma_layer_regA<4, 4>(ahx, alx, PH, PL, lane, acc);
    {
        int r0 = (lane >> 4) << 2;
#pragma unroll
        for (int n = 0; n < 4; ++n) {
            int col = n * 16 + (lane & 15);
            float bv = bu1[col];
#pragma unroll
            for (int q = 0; q < 4; ++q) {
                int node = n0 + m16 + r0 + q;
                float sv = (node < N) ? S[(size_t)node * H + col] : 0.f;
                Ws[(r0 + q) * LDC + col] = fmaxf(acc[n][q] + bv + sv, 0.f);
            }
        }
    }

    // layer 2: H1 @ Wu2, relu -> H2 (in place)
#pragma unroll
    for (int n = 0; n < 4; ++n) acc[n] = (f32x4){0.f, 0.f, 0.f, 0.f};
    mfma_layer<4, 2>(Ws, LDC, PH + (size_t)16 * PFRAG, PL + (size_t)16 * PFRAG, lane, acc);
    store_C_lds<4>(acc, bu2, Ws, LDC, lane);

    // layer 3: H2 @ Wu3 (linear) + select by node_type
#pragma unroll
    for (int n = 0; n < 8; ++n) acc[n] = (f32x4){0.f, 0.f, 0.f, 0.f};
    mfma_layer<8, 2>(Ws, LDC, PH + (size_t)24 * PFRAG, PL + (size_t)24 * PFRAG, lane, acc);
    {
        int r0 = (lane >> 4) << 2;
#pragma unroll
        for (int q = 0; q < 4; ++q) {
            int node = n0 + m16 + r0 + q;
            if (node >= N) continue;
            int t = node_type[node];
#pragma unroll
            for (int n = 0; n < 8; ++n) {
                int col = n * 16 + (lane & 15);
                float o = (t <= 1) ? (acc[n][q] + bu3[col])
                                   : X[(size_t)node * D + col];
                out[(size_t)node * D + col] = o;
            }
        }
    }
}

extern "C" void kernel_launch(void* const* d_in, const int* in_sizes, int n_in,
                              void* d_out, int out_size, void* d_ws, size_t ws_size,
                              hipStream_t stream) {
    const float* X     = (const float*)d_in[0];
    const int*   src   = (const int*)d_in[1];
    const int*   dst   = (const int*)d_in[2];
    const int*   etype = (const int*)d_in[3];
    const int*   ntype = (const int*)d_in[4];
    const float* W1    = (const float*)d_in[5];
    const float* b1    = (const float*)d_in[6];
    const float* W2    = (const float*)d_in[7];
    const float* b2    = (const float*)d_in[8];
    const float* W3    = (const float*)d_in[9];
    const float* b3    = (const float*)d_in[10];
    const float* Wu1   = (const float*)d_in[11];
    const float* bu1   = (const float*)d_in[12];
    const float* Wu2   = (const float*)d_in[13];
    const float* bu2   = (const float*)d_in[14];
    const float* Wu3   = (const float*)d_in[15];
    const float* bu3   = (const float*)d_in[16];
    float* out = (float*)d_out;

    const int N = in_sizes[4];
    const int E = in_sizes[1];

    // workspace layout
    float* U    = (float*)d_ws;                       // N*R*H floats (51.2 MB)
    float* S    = U + (size_t)N * R * H;              // N*H floats (12.8 MB)
    int* cnt    = (int*)(S + (size_t)N * H);          // N
    int* eidx   = cnt + N;                            // N*CAP ints (25.6 MB)
    short* Phi  = (short*)(eidx + (size_t)N * CAP);   // NFRAG*PFRAG shorts
    short* Plo  = Phi + (size_t)NFRAG * PFRAG;

    hipMemsetAsync(cnt, 0, (size_t)N * sizeof(int), stream);

    int eb = (E + 255) / 256;
    k_fill<<<eb, 256, 0, stream>>>(src, dst, etype, cnt, eidx, E);
    k_wprep<<<19, 256, 0, stream>>>(W1, W2, W3, Wu1, Wu2, Wu3, Phi, Plo);

    int tiles = (N + NT - 1) / NT;
    k_mlp_rel<<<tiles * R, 256, 0, stream>>>(X, b1, b2, b3, Phi, Plo, U, N, tiles);
    k_gather<<<(N + 3) / 4, 256, 0, stream>>>(U, cnt, eidx, S, N);
    k_upd<<<tiles, 256, 0, stream>>>(X, S, cnt, ntype, Phi, Plo, bu1, bu2, bu3, out, N);
}

// Round 14
// 176.069 us; speedup vs baseline: 1.5260x; 1.0416x over previous
//
#include <hip/hip_runtime.h>
#include <hip/hip_bf16.h>

// Problem constants (static per reference)
#define D 128
#define H 64
#define R 4
#define NT 64      // nodes per tile/block (4 waves x 16 rows)
#define LDC 132    // LDS stride (floats) for the per-wave strip
#define CAP 128    // per-node edge bucket capacity (deg ~ Poisson(16); P(>128) ~ 1e-60)

// MFMA fragment types
typedef __attribute__((ext_vector_type(8))) short bf16x8;
typedef __attribute__((ext_vector_type(4))) float f32x4;

// Weight-prep layout: per relation, 56 frags of 512 bf16 elems (64 lanes x 8):
//   W1 frags [0,16), W2 [16,24), W3 [24,40), Wu1_{r+1} [40,56)
// Updater block appended at UBASE: Wu1[0:128] [0,16), Wu2 [16,24), Wu3 [24,40)
// Frag f = ntile*KSTEPS + kstep; lane l covers col = ntile*16+(l&15),
// k = kstep*32 + (l>>4)*8 + i.  (Same phi used for A -> phi cancels.)
// Each frag is 512 contiguous shorts = 64 lanes x 16 B -> exactly one
// global_load_lds dwordx4 per fragment (wave-uniform LDS base + lane*16).
#define PREL 56
#define PFRAG 512
#define UBASE (R * PREL)     // 224
#define UPREL 40
#define NFRAG (UBASE + UPREL)

__device__ __forceinline__ float4 relu4(float4 v) {
    return make_float4(fmaxf(v.x, 0.f), fmaxf(v.y, 0.f), fmaxf(v.z, 0.f), fmaxf(v.w, 0.f));
}

// split fp32 -> bf16 hi (RTZ) + bf16 lo (residual, RTZ)
__device__ __forceinline__ void split1(float x, short& hi, short& lo) {
    unsigned u = __float_as_uint(x);
    unsigned hb = u & 0xffff0000u;
    float res = x - __uint_as_float(hb);
    hi = (short)(u >> 16);
    lo = (short)(__float_as_uint(res) >> 16);
}

__device__ __forceinline__ void split8(const float* x8, bf16x8& hi, bf16x8& lo) {
#pragma unroll
    for (int i = 0; i < 8; ++i) {
        short h, l;
        split1(x8[i], h, l);
        hi[i] = h; lo[i] = l;
    }
}

__device__ __forceinline__ void load_split_A(const float* ap, bf16x8& ah, bf16x8& al) {
    float x8[8];
    *(float4*)&x8[0] = *(const float4*)ap;
    *(float4*)&x8[4] = *(const float4*)(ap + 4);
    split8(x8, ah, al);
}

// async global->LDS, 16 B per lane (global src per-lane, LDS dst wave-uniform base)
__device__ __forceinline__ void gload_lds16(const void* g, void* l) {
    __builtin_amdgcn_global_load_lds(
        (const __attribute__((address_space(1))) void*)g,
        (__attribute__((address_space(3))) void*)l, 16, 0, 0);
}

// stage nfrag 1KB fragments of hi+lo into LDS, cooperatively across 4 waves
__device__ __forceinline__ void stage_B(const short* __restrict__ srcH,
                                        const short* __restrict__ srcL,
                                        short* BbH, short* BbL,
                                        int nfrag, int w, int lane) {
    for (int f = w; f < nfrag; f += 4) {
        gload_lds16(srcH + ((size_t)f << 9) + (lane << 3), BbH + (f << 9));
        gload_lds16(srcL + ((size_t)f << 9) + (lane << 3), BbL + (f << 9));
    }
}

// A from LDS fp32 strip (split on the fly), B from LDS (staged) -> ds_read_b128.
template<int NT_TILES, int KSTEPS>
__device__ __forceinline__ void mfma_layer_ldsB(const float* Als, int ld,
                                                const short* BbH, const short* BbL,
                                                int lane, f32x4* acc) {
#pragma unroll
    for (int ks = 0; ks < KSTEPS; ++ks) {
        bf16x8 ah, al;
        load_split_A(Als + (lane & 15) * ld + ks * 32 + ((lane >> 4) << 3), ah, al);
        bf16x8 bh[NT_TILES], bl[NT_TILES];
#pragma unroll
        for (int n = 0; n < NT_TILES; ++n) {
            int f = n * KSTEPS + ks;
            bh[n] = *(const bf16x8*)(BbH + ((f * 64 + lane) << 3));
            bl[n] = *(const bf16x8*)(BbL + ((f * 64 + lane) << 3));
        }
#pragma unroll
        for (int n = 0; n < NT_TILES; ++n) {
            acc[n] = __builtin_amdgcn_mfma_f32_16x16x32_bf16(ah, bh[n], acc[n], 0, 0, 0);
            acc[n] = __builtin_amdgcn_mfma_f32_16x16x32_bf16(ah, bl[n], acc[n], 0, 0, 0);
            acc[n] = __builtin_amdgcn_mfma_f32_16x16x32_bf16(al, bh[n], acc[n], 0, 0, 0);
        }
    }
}

// A from pre-split registers, B from LDS (staged).
template<int NT_TILES, int KSTEPS>
__device__ __forceinline__ void mfma_layer_regA_ldsB(const bf16x8* ah, const bf16x8* al,
                                                     const short* BbH, const short* BbL,
                                                     int lane, f32x4* acc) {
#pragma unroll
    for (int ks = 0; ks < KSTEPS; ++ks) {
        bf16x8 bh[NT_TILES], bl[NT_TILES];
#pragma unroll
        for (int n = 0; n < NT_TILES; ++n) {
            int f = n * KSTEPS + ks;
            bh[n] = *(const bf16x8*)(BbH + ((f * 64 + lane) << 3));
            bl[n] = *(const bf16x8*)(BbL + ((f * 64 + lane) << 3));
        }
#pragma unroll
        for (int n = 0; n < NT_TILES; ++n) {
            acc[n] = __builtin_amdgcn_mfma_f32_16x16x32_bf16(ah[ks], bh[n], acc[n], 0, 0, 0);
            acc[n] = __builtin_amdgcn_mfma_f32_16x16x32_bf16(ah[ks], bl[n], acc[n], 0, 0, 0);
            acc[n] = __builtin_amdgcn_mfma_f32_16x16x32_bf16(al[ks], bh[n], acc[n], 0, 0, 0);
        }
    }
}

// B from global (k_upd keeps the old path this round)
template<int NT_TILES, int KSTEPS>
__device__ __forceinline__ void mfma_layer(const float* Als, int ld,
                                           const short* __restrict__ Bhi,
                                           const short* __restrict__ Blo,
                                           int lane, f32x4* acc) {
#pragma unroll
    for (int ks = 0; ks < KSTEPS; ++ks) {
        bf16x8 ah, al;
        load_split_A(Als + (lane & 15) * ld + ks * 32 + ((lane >> 4) << 3), ah, al);
        bf16x8 bh[NT_TILES], bl[NT_TILES];
#pragma unroll
        for (int n = 0; n < NT_TILES; ++n) {
            int f = n * KSTEPS + ks;
            bh[n] = *(const bf16x8*)(Bhi + (((size_t)f * 64 + lane) << 3));
            bl[n] = *(const bf16x8*)(Blo + (((size_t)f * 64 + lane) << 3));
        }
#pragma unroll
        for (int n = 0; n < NT_TILES; ++n) {
            acc[n] = __builtin_amdgcn_mfma_f32_16x16x32_bf16(ah, bh[n], acc[n], 0, 0, 0);
            acc[n] = __builtin_amdgcn_mfma_f32_16x16x32_bf16(ah, bl[n], acc[n], 0, 0, 0);
            acc[n] = __builtin_amdgcn_mfma_f32_16x16x32_bf16(al, bh[n], acc[n], 0, 0, 0);
        }
    }
}

template<int NT_TILES, int KSTEPS>
__device__ __forceinline__ void mfma_layer_regA(const bf16x8* ah, const bf16x8* al,
                                                const short* __restrict__ Bhi,
                                                const short* __restrict__ Blo,
                                                int lane, f32x4* acc) {
#pragma unroll
    for (int ks = 0; ks < KSTEPS; ++ks) {
        bf16x8 bh[NT_TILES], bl[NT_TILES];
#pragma unroll
        for (int n = 0; n < NT_TILES; ++n) {
            int f = n * KSTEPS + ks;
            bh[n] = *(const bf16x8*)(Bhi + (((size_t)f * 64 + lane) << 3));
            bl[n] = *(const bf16x8*)(Blo + (((size_t)f * 64 + lane) << 3));
        }
#pragma unroll
        for (int n = 0; n < NT_TILES; ++n) {
            acc[n] = __builtin_amdgcn_mfma_f32_16x16x32_bf16(ah[ks], bh[n], acc[n], 0, 0, 0);
            acc[n] = __builtin_amdgcn_mfma_f32_16x16x32_bf16(ah[ks], bl[n], acc[n], 0, 0, 0);
            acc[n] = __builtin_amdgcn_mfma_f32_16x16x32_bf16(al[ks], bh[n], acc[n], 0, 0, 0);
        }
    }
}

// bias + relu + store C strip to LDS fp32 (C/D layout: col=lane&15, row=(lane>>4)*4+reg)
template<int NT_TILES>
__device__ __forceinline__ void store_C_lds(const f32x4* acc, const float* __restrict__ bias,
                                            float* Ld, int ld, int lane) {
    int r0 = (lane >> 4) << 2;
#pragma unroll
    for (int n = 0; n < NT_TILES; ++n) {
        int col = n * 16 + (lane & 15);
        float bv = bias[col];
#pragma unroll
        for (int q = 0; q < 4; ++q)
            Ld[(r0 + q) * ld + col] = fmaxf(acc[n][q] + bv, 0.f);
    }
}

// ---------------- Bucketed CSR: one pass does count + fill ----------------

__global__ __launch_bounds__(256) void k_fill(const int* __restrict__ src, const int* __restrict__ dst,
                                              const int* __restrict__ etype, int* __restrict__ cnt,
                                              int* __restrict__ eidx, int E) {
    int e = blockIdx.x * 256 + threadIdx.x;
    if (e < E) {
        int d = dst[e];
        int p = atomicAdd(&cnt[d], 1);
        if (p < CAP) eidx[(size_t)d * CAP + p] = src[e] * 4 + etype[e];
    }
}

// ---------------- Weight prep: split + frag-swizzle all B matrices ----------------

__global__ __launch_bounds__(256) void k_wprep(
    const float* __restrict__ W1, const float* __restrict__ W2,
    const float* __restrict__ W3, const float* __restrict__ Wu1,
    const float* __restrict__ Wu2, const float* __restrict__ Wu3,
    short* __restrict__ Phi, short* __restrict__ Plo)
{
    int pair = blockIdx.x;
    const float* src; int KS, NTl, fragbase, ncol;
    if (pair < 16) {
        int r = pair >> 2, mat = pair & 3;
        if (mat == 0)      { src = W1  + (size_t)r * (D * H);       KS = 4; NTl = 4; fragbase = r * PREL + 0;  ncol = 64;  }
        else if (mat == 1) { src = W2  + (size_t)r * (H * H);       KS = 2; NTl = 4; fragbase = r * PREL + 16; ncol = 64;  }
        else if (mat == 2) { src = W3  + (size_t)r * (H * D);       KS = 2; NTl = 8; fragbase = r * PREL + 24; ncol = 128; }
        else               { src = Wu1 + (size_t)(r + 1) * D * H;   KS = 4; NTl = 4; fragbase = r * PREL + 40; ncol = 64;  }
    } else {
        int mat = pair - 16;
        if (mat == 0)      { src = Wu1; KS = 4; NTl = 4; fragbase = UBASE + 0;  ncol = 64;  }  // rows 0..127
        else if (mat == 1) { src = Wu2; KS = 2; NTl = 4; fragbase = UBASE + 16; ncol = 64;  }
        else               { src = Wu3; KS = 2; NTl = 8; fragbase = UBASE + 24; ncol = 128; }
    }
    int nf = NTl * KS;
    for (int u = threadIdx.x; u < nf * 64; u += 256) {
        int f = u >> 6, lane = u & 63;
        int n = f / KS, ks = f - n * KS;
        int col = n * 16 + (lane & 15);
        int k0 = ks * 32 + ((lane >> 4) << 3);
        size_t dstp = (((size_t)(fragbase + f)) * 64 + (size_t)lane) * 8;
#pragma unroll
        for (int i = 0; i < 8; ++i) {
            short h, l;
            split1(src[(size_t)(k0 + i) * ncol + col], h, l);
            Phi[dstp + i] = h;
            Plo[dstp + i] = l;
        }
    }
}

// ---------------- Stage A: per-(tile, relation) message MLP + Wu1 fold ----------------
// B fragments staged into LDS once per block (global_load_lds, 1 KB/frag) and
// consumed by all 4 waves as conflict-free ds_read_b128 -> 4x less B VMEM.
// Schedule: [stage Wl][bar][compute l][bar] x 4 layers. Strips per wave for
// H1/H2/T. LDS = 33792 (strips) + 32768 (B) = 66560 B => 2 blocks/CU.

__global__ __launch_bounds__(256, 2) void k_mlp_rel(
    const float* __restrict__ X,
    const float* __restrict__ b1, const float* __restrict__ b2, const float* __restrict__ b3,
    const short* __restrict__ Phi, const short* __restrict__ Plo,
    float* __restrict__ U, int N, int tiles)
{
    __shared__ float Bsh[NT * LDC];     // per-wave 16-row strips
    __shared__ short BbH[16 * PFRAG];   // staged B hi (<= 16 frags/layer)
    __shared__ short BbL[16 * PFRAG];   // staged B lo

    const int tid = threadIdx.x;
    const int lane = tid & 63;
    const int w = tid >> 6;
    const int m16 = w * 16;
    const int r = blockIdx.x / tiles;          // relation-major
    const int n0 = (blockIdx.x - r * tiles) * NT;

    const short* PH = Phi + (size_t)(r * PREL) * PFRAG;
    const short* PL = Plo + (size_t)(r * PREL) * PFRAG;
    const float* b1r = b1 + r * H;
    const float* b2r = b2 + r * H;
    const float* b3r = b3 + r * D;

    float* Ws = &Bsh[m16 * LDC];   // this wave's strip

    // issue W1 staging first so it overlaps the X register staging below
    stage_B(PH, PL, BbH, BbL, 16, w, lane);

    // stage X A-fragments direct from global into registers, split once
    bf16x8 ahx[4], alx[4];
    {
        int row = n0 + m16 + (lane & 15);
        const float* xp = X + (size_t)row * D + ((lane >> 4) << 3);
        bool ok = (row < N);
#pragma unroll
        for (int ks = 0; ks < 4; ++ks) {
            float x8[8];
            if (ok) {
                *(float4*)&x8[0] = *(const float4*)(xp + ks * 32);
                *(float4*)&x8[4] = *(const float4*)(xp + ks * 32 + 4);
            } else {
#pragma unroll
                for (int i = 0; i < 8; ++i) x8[i] = 0.f;
            }
            split8(x8, ahx[ks], alx[ks]);
        }
    }
    __syncthreads();   // W1 staged (syncthreads drains vmcnt)

    // layer 1: X(16x128) @ W1(128x64) — A regs, B LDS
    f32x4 acc[8];
#pragma unroll
    for (int n = 0; n < 4; ++n) acc[n] = (f32x4){0.f, 0.f, 0.f, 0.f};
    mfma_layer_regA_ldsB<4, 4>(ahx, alx, BbH, BbL, lane, acc);
    store_C_lds<4>(acc, b1r, Ws, LDC, lane);   // H1
    __syncthreads();   // all waves done reading W1

    // layer 2: H1(16x64) @ W2(64x64)
    stage_B(PH + 16 * PFRAG, PL + 16 * PFRAG, BbH, BbL, 8, w, lane);
    __syncthreads();
#pragma unroll
    for (int n = 0; n < 4; ++n) acc[n] = (f32x4){0.f, 0.f, 0.f, 0.f};
    mfma_layer_ldsB<4, 2>(Ws, LDC, BbH, BbL, lane, acc);
    store_C_lds<4>(acc, b2r, Ws, LDC, lane);   // H2
    __syncthreads();

    // layer 3: H2(16x64) @ W3(64x128), relu -> T
    stage_B(PH + 24 * PFRAG, PL + 24 * PFRAG, BbH, BbL, 16, w, lane);
    __syncthreads();
#pragma unroll
    for (int n = 0; n < 8; ++n) acc[n] = (f32x4){0.f, 0.f, 0.f, 0.f};
    mfma_layer_ldsB<8, 2>(Ws, LDC, BbH, BbL, lane, acc);
    store_C_lds<8>(acc, b3r, Ws, LDC, lane);   // T
    __syncthreads();

    // U projection: T(16x128) @ Wu1_{r+1}(128x64)
    stage_B(PH + 40 * PFRAG, PL + 40 * PFRAG, BbH, BbL, 16, w, lane);
    __syncthreads();
#pragma unroll
    for (int n = 0; n < 4; ++n) acc[n] = (f32x4){0.f, 0.f, 0.f, 0.f};
    mfma_layer_ldsB<4, 4>(Ws, LDC, BbH, BbL, lane, acc);
    {
        int r0 = (lane >> 4) << 2;
#pragma unroll
        for (int n = 0; n < 4; ++n) {
            int col = n * 16 + (lane & 15);
#pragma unroll
            for (int q = 0; q < 4; ++q) {
                int node = n0 + m16 + r0 + q;
                if (node < N)
                    U[((size_t)node * R + r) * H + col] = acc[n][q];
            }
        }
    }
}

// ---------------- Stage B: gather S[n] = sum over in-edges of U[src*4+rel] ----------------

__global__ __launch_bounds__(256) void k_gather(
    const float* __restrict__ U,
    const int* __restrict__ cnt, const int* __restrict__ eidx,
    float* __restrict__ S, int N)
{
    const int wid = threadIdx.x >> 6, lane = threadIdx.x & 63;
    const int n = blockIdx.x * 4 + wid;
    if (n >= N) return;
    int g = cnt[n]; if (g > CAP) g = CAP;
    const int* ep = eidx + (size_t)n * CAP;
    const int half = lane >> 5;
    const int c2 = lane & 31;
    float ax = 0.f, ay = 0.f;
    for (int base = 0; base < g; base += 64) {
        int m = g - base; if (m > 64) m = 64;
        int v = 0;
        if (lane < m) v = ep[base + lane];
        for (int j0 = 0; j0 < m; j0 += 16) {
            int lim = m - j0; if (lim > 16) lim = 16;
            float2 t[8];
#pragma unroll
            for (int p = 0; p < 8; ++p) {
                int vi = __shfl(v, j0 + 2 * p + half);
                bool ok = (2 * p + half) < lim;
                t[p] = ok ? *(const float2*)&U[(size_t)vi * H + (c2 << 1)]
                          : make_float2(0.f, 0.f);
            }
#pragma unroll
            for (int p = 0; p < 8; ++p) { ax += t[p].x; ay += t[p].y; }
        }
    }
    ax += __shfl_xor(ax, 32);
    ay += __shfl_xor(ay, 32);
    if (half == 0)
        *(float2*)&S[(size_t)n * H + (c2 << 1)] = make_float2(ax, ay);
}

// ---------------- Stage C: updater MLP + select (split-bf16 MFMA, barrier-free) ----------------

__global__ __launch_bounds__(256, 4) void k_upd(
    const float* __restrict__ X, const float* __restrict__ S,
    const int* __restrict__ cnt, const int* __restrict__ node_type,
    const short* __restrict__ Phi, const short* __restrict__ Plo,
    const float* __restrict__ bu1, const float* __restrict__ bu2, const float* __restrict__ bu3,
    float* __restrict__ out, int N)
{
    __shared__ float Hsh[NT * LDC];   // per-wave strips (H1/H2)

    const int tid = threadIdx.x;
    const int lane = tid & 63;
    const int w = tid >> 6;
    const int m16 = w * 16;
    const int n0 = blockIdx.x * NT;

    const short* PH = Phi + (size_t)UBASE * PFRAG;
    const short* PL = Plo + (size_t)UBASE * PFRAG;

    float* Ws = &Hsh[m16 * LDC];

    // stage chunk0 = relu(x) * (indeg > 0) direct into register A-fragments
    bf16x8 ahx[4], alx[4];
    {
        int row = n0 + m16 + (lane & 15);
        bool ok = (row < N) && (cnt[row] > 0);
        const float* xp = X + (size_t)row * D + ((lane >> 4) << 3);
#pragma unroll
        for (int ks = 0; ks < 4; ++ks) {
            float x8[8];
            if (ok) {
                float4 a = *(const float4*)(xp + ks * 32);
                float4 b = *(const float4*)(xp + ks * 32 + 4);
                a = relu4(a); b = relu4(b);
                *(float4*)&x8[0] = a;
                *(float4*)&x8[4] = b;
            } else {
#pragma unroll
                for (int i = 0; i < 8; ++i) x8[i] = 0.f;
            }
            split8(x8, ahx[ks], alx[ks]);
        }
    }

    // layer 1: chunk0 @ Wu1[0:128] + S + bu1, relu -> H1
    f32x4 acc[8];
#pragma unroll
    for (int n = 0; n < 4; ++n) acc[n] = (f32x4){0.f, 0.f, 0.f, 0.f};
    mfma_layer_regA<4, 4>(ahx, alx, PH, PL, lane, acc);
    {
        int r0 = (lane >> 4) << 2;
#pragma unroll
        for (int n = 0; n < 4; ++n) {
            int col = n * 16 + (lane & 15);
            float bv = bu1[col];
#pragma unroll
            for (int q = 0; q < 4; ++q) {
                int node = n0 + m16 + r0 + q;
                float sv = (node < N) ? S[(size_t)node * H + col] : 0.f;
                Ws[(r0 + q) * LDC + col] = fmaxf(acc[n][q] + bv + sv, 0.f);
            }
        }
    }

    // layer 2: H1 @ Wu2, relu -> H2 (in place)
#pragma unroll
    for (int n = 0; n < 4; ++n) acc[n] = (f32x4){0.f, 0.f, 0.f, 0.f};
    mfma_layer<4, 2>(Ws, LDC, PH + (size_t)16 * PFRAG, PL + (size_t)16 * PFRAG, lane, acc);
    store_C_lds<4>(acc, bu2, Ws, LDC, lane);

    // layer 3: H2 @ Wu3 (linear) + select by node_type
#pragma unroll
    for (int n = 0; n < 8; ++n) acc[n] = (f32x4){0.f, 0.f, 0.f, 0.f};
    mfma_layer<8, 2>(Ws, LDC, PH + (size_t)24 * PFRAG, PL + (size_t)24 * PFRAG, lane, acc);
    {
        int r0 = (lane >> 4) << 2;
#pragma unroll
        for (int q = 0; q < 4; ++q) {
            int node = n0 + m16 + r0 + q;
            if (node >= N) continue;
            int t = node_type[node];
#pragma unroll
            for (int n = 0; n < 8; ++n) {
                int col = n * 16 + (lane & 15);
                float o = (t <= 1) ? (acc[n][q] + bu3[col])
                                   : X[(size_t)node * D + col];
                out[(size_t)node * D + col] = o;
            }
        }
    }
}

extern "C" void kernel_launch(void* const* d_in, const int* in_sizes, int n_in,
                              void* d_out, int out_size, void* d_ws, size_t ws_size,
                              hipStream_t stream) {
    const float* X     = (const float*)d_in[0];
    const int*   src   = (const int*)d_in[1];
    const int*   dst   = (const int*)d_in[2];
    const int*   etype = (const int*)d_in[3];
    const int*   ntype = (const int*)d_in[4];
    const float* W1    = (const float*)d_in[5];
    const float* b1    = (const float*)d_in[6];
    const float* W2    = (const float*)d_in[7];
    const float* b2    = (const float*)d_in[8];
    const float* W3    = (const float*)d_in[9];
    const float* b3    = (const float*)d_in[10];
    const float* Wu1   = (const float*)d_in[11];
    const float* bu1   = (const float*)d_in[12];
    const float* Wu2   = (const float*)d_in[13];
    const float* bu2   = (const float*)d_in[14];
    const float* Wu3   = (const float*)d_in[15];
    const float* bu3   = (const float*)d_in[16];
    float* out = (float*)d_out;

    const int N = in_sizes[4];
    const int E = in_sizes[1];

    // workspace layout
    float* U    = (float*)d_ws;                       // N*R*H floats (51.2 MB)
    float* S    = U + (size_t)N * R * H;              // N*H floats (12.8 MB)
    int* cnt    = (int*)(S + (size_t)N * H);          // N
    int* eidx   = cnt + N;                            // N*CAP ints (25.6 MB)
    short* Phi  = (short*)(eidx + (size_t)N * CAP);   // NFRAG*PFRAG shorts
    short* Plo  = Phi + (size_t)NFRAG * PFRAG;

    hipMemsetAsync(cnt, 0, (size_t)N * sizeof(int), stream);

    int eb = (E + 255) / 256;
    k_fill<<<eb, 256, 0, stream>>>(src, dst, etype, cnt, eidx, E);
    k_wprep<<<19, 256, 0, stream>>>(W1, W2, W3, Wu1, Wu2, Wu3, Phi, Plo);

    int tiles = (N + NT - 1) / NT;
    k_mlp_rel<<<tiles * R, 256, 0, stream>>>(X, b1, b2, b3, Phi, Plo, U, N, tiles);
    k_gather<<<(N + 3) / 4, 256, 0, stream>>>(U, cnt, eidx, S, N);
    k_upd<<<tiles, 256, 0, stream>>>(X, S, cnt, ntype, Phi, Plo, bu1, bu2, bu3, out, N);
}

// Round 15
// 169.165 us; speedup vs baseline: 1.5883x; 1.0408x over previous
//
#include <hip/hip_runtime.h>
#include <hip/hip_bf16.h>

// Problem constants (static per reference)
#define D 128
#define H 64
#define R 4
#define NT 64      // nodes per tile/block (4 waves x 16 rows)
#define LDC 132    // LDS stride (floats) for the per-wave strip
#define CAP 128    // per-node edge bucket capacity (deg ~ Poisson(16); P(>128) ~ 1e-60)

// MFMA fragment types
typedef __attribute__((ext_vector_type(8))) short bf16x8;
typedef __attribute__((ext_vector_type(4))) float f32x4;

// Weight-prep layout: per relation, 56 frags of 512 bf16 elems (64 lanes x 8):
//   W1 frags [0,16), W2 [16,24), W3 [24,40), Wu1_{r+1} [40,56)
// Updater block appended at UBASE: Wu1[0:128] [0,16), Wu2 [16,24), Wu3 [24,40)
// Frag f = ntile*KSTEPS + kstep; lane l covers col = ntile*16+(l&15),
// k = kstep*32 + (l>>4)*8 + i.  (Same phi used for A -> phi cancels.)
// Each frag is 512 contiguous shorts = 64 lanes x 16 B -> exactly one
// global_load_lds dwordx4 per fragment (wave-uniform LDS base + lane*16).
#define PREL 56
#define PFRAG 512
#define UBASE (R * PREL)     // 224
#define UPREL 40
#define NFRAG (UBASE + UPREL)

__device__ __forceinline__ float4 relu4(float4 v) {
    return make_float4(fmaxf(v.x, 0.f), fmaxf(v.y, 0.f), fmaxf(v.z, 0.f), fmaxf(v.w, 0.f));
}

// fp32 -> bf16 with round-to-nearest-even
__device__ __forceinline__ unsigned short f2bf_rne(float x) {
    unsigned u = __float_as_uint(x);
    return (unsigned short)((u + 0x7fffu + ((u >> 16) & 1u)) >> 16);
}

// split fp32 -> bf16 hi (RTZ) + bf16 lo (residual, RTZ)
__device__ __forceinline__ void split1(float x, short& hi, short& lo) {
    unsigned u = __float_as_uint(x);
    unsigned hb = u & 0xffff0000u;
    float res = x - __uint_as_float(hb);
    hi = (short)(u >> 16);
    lo = (short)(__float_as_uint(res) >> 16);
}

__device__ __forceinline__ void split8(const float* x8, bf16x8& hi, bf16x8& lo) {
#pragma unroll
    for (int i = 0; i < 8; ++i) {
        short h, l;
        split1(x8[i], h, l);
        hi[i] = h; lo[i] = l;
    }
}

__device__ __forceinline__ void load_split_A(const float* ap, bf16x8& ah, bf16x8& al) {
    float x8[8];
    *(float4*)&x8[0] = *(const float4*)ap;
    *(float4*)&x8[4] = *(const float4*)(ap + 4);
    split8(x8, ah, al);
}

// async global->LDS, 16 B per lane (global src per-lane, LDS dst wave-uniform base)
__device__ __forceinline__ void gload_lds16(const void* g, void* l) {
    __builtin_amdgcn_global_load_lds(
        (const __attribute__((address_space(1))) void*)g,
        (__attribute__((address_space(3))) void*)l, 16, 0, 0);
}

// stage nfrag 1KB fragments of hi+lo into LDS, cooperatively across 4 waves
__device__ __forceinline__ void stage_B(const short* __restrict__ srcH,
                                        const short* __restrict__ srcL,
                                        short* BbH, short* BbL,
                                        int nfrag, int w, int lane) {
    for (int f = w; f < nfrag; f += 4) {
        gload_lds16(srcH + ((size_t)f << 9) + (lane << 3), BbH + (f << 9));
        gload_lds16(srcL + ((size_t)f << 9) + (lane << 3), BbL + (f << 9));
    }
}

// A from LDS fp32 strip (split on the fly), B from LDS (staged) -> ds_read_b128.
template<int NT_TILES, int KSTEPS>
__device__ __forceinline__ void mfma_layer_ldsB(const float* Als, int ld,
                                                const short* BbH, const short* BbL,
                                                int lane, f32x4* acc) {
#pragma unroll
    for (int ks = 0; ks < KSTEPS; ++ks) {
        bf16x8 ah, al;
        load_split_A(Als + (lane & 15) * ld + ks * 32 + ((lane >> 4) << 3), ah, al);
        bf16x8 bh[NT_TILES], bl[NT_TILES];
#pragma unroll
        for (int n = 0; n < NT_TILES; ++n) {
            int f = n * KSTEPS + ks;
            bh[n] = *(const bf16x8*)(BbH + ((f * 64 + lane) << 3));
            bl[n] = *(const bf16x8*)(BbL + ((f * 64 + lane) << 3));
        }
#pragma unroll
        for (int n = 0; n < NT_TILES; ++n) {
            acc[n] = __builtin_amdgcn_mfma_f32_16x16x32_bf16(ah, bh[n], acc[n], 0, 0, 0);
            acc[n] = __builtin_amdgcn_mfma_f32_16x16x32_bf16(ah, bl[n], acc[n], 0, 0, 0);
            acc[n] = __builtin_amdgcn_mfma_f32_16x16x32_bf16(al, bh[n], acc[n], 0, 0, 0);
        }
    }
}

// A from pre-split registers, B from LDS (staged).
template<int NT_TILES, int KSTEPS>
__device__ __forceinline__ void mfma_layer_regA_ldsB(const bf16x8* ah, const bf16x8* al,
                                                     const short* BbH, const short* BbL,
                                                     int lane, f32x4* acc) {
#pragma unroll
    for (int ks = 0; ks < KSTEPS; ++ks) {
        bf16x8 bh[NT_TILES], bl[NT_TILES];
#pragma unroll
        for (int n = 0; n < NT_TILES; ++n) {
            int f = n * KSTEPS + ks;
            bh[n] = *(const bf16x8*)(BbH + ((f * 64 + lane) << 3));
            bl[n] = *(const bf16x8*)(BbL + ((f * 64 + lane) << 3));
        }
#pragma unroll
        for (int n = 0; n < NT_TILES; ++n) {
            acc[n] = __builtin_amdgcn_mfma_f32_16x16x32_bf16(ah[ks], bh[n], acc[n], 0, 0, 0);
            acc[n] = __builtin_amdgcn_mfma_f32_16x16x32_bf16(ah[ks], bl[n], acc[n], 0, 0, 0);
            acc[n] = __builtin_amdgcn_mfma_f32_16x16x32_bf16(al[ks], bh[n], acc[n], 0, 0, 0);
        }
    }
}

// B from global (k_upd path)
template<int NT_TILES, int KSTEPS>
__device__ __forceinline__ void mfma_layer(const float* Als, int ld,
                                           const short* __restrict__ Bhi,
                                           const short* __restrict__ Blo,
                                           int lane, f32x4* acc) {
#pragma unroll
    for (int ks = 0; ks < KSTEPS; ++ks) {
        bf16x8 ah, al;
        load_split_A(Als + (lane & 15) * ld + ks * 32 + ((lane >> 4) << 3), ah, al);
        bf16x8 bh[NT_TILES], bl[NT_TILES];
#pragma unroll
        for (int n = 0; n < NT_TILES; ++n) {
            int f = n * KSTEPS + ks;
            bh[n] = *(const bf16x8*)(Bhi + (((size_t)f * 64 + lane) << 3));
            bl[n] = *(const bf16x8*)(Blo + (((size_t)f * 64 + lane) << 3));
        }
#pragma unroll
        for (int n = 0; n < NT_TILES; ++n) {
            acc[n] = __builtin_amdgcn_mfma_f32_16x16x32_bf16(ah, bh[n], acc[n], 0, 0, 0);
            acc[n] = __builtin_amdgcn_mfma_f32_16x16x32_bf16(ah, bl[n], acc[n], 0, 0, 0);
            acc[n] = __builtin_amdgcn_mfma_f32_16x16x32_bf16(al, bh[n], acc[n], 0, 0, 0);
        }
    }
}

template<int NT_TILES, int KSTEPS>
__device__ __forceinline__ void mfma_layer_regA(const bf16x8* ah, const bf16x8* al,
                                                const short* __restrict__ Bhi,
                                                const short* __restrict__ Blo,
                                                int lane, f32x4* acc) {
#pragma unroll
    for (int ks = 0; ks < KSTEPS; ++ks) {
        bf16x8 bh[NT_TILES], bl[NT_TILES];
#pragma unroll
        for (int n = 0; n < NT_TILES; ++n) {
            int f = n * KSTEPS + ks;
            bh[n] = *(const bf16x8*)(Bhi + (((size_t)f * 64 + lane) << 3));
            bl[n] = *(const bf16x8*)(Blo + (((size_t)f * 64 + lane) << 3));
        }
#pragma unroll
        for (int n = 0; n < NT_TILES; ++n) {
            acc[n] = __builtin_amdgcn_mfma_f32_16x16x32_bf16(ah[ks], bh[n], acc[n], 0, 0, 0);
            acc[n] = __builtin_amdgcn_mfma_f32_16x16x32_bf16(ah[ks], bl[n], acc[n], 0, 0, 0);
            acc[n] = __builtin_amdgcn_mfma_f32_16x16x32_bf16(al[ks], bh[n], acc[n], 0, 0, 0);
        }
    }
}

// bias + relu + store C strip to LDS fp32 (C/D layout: col=lane&15, row=(lane>>4)*4+reg)
template<int NT_TILES>
__device__ __forceinline__ void store_C_lds(const f32x4* acc, const float* __restrict__ bias,
                                            float* Ld, int ld, int lane) {
    int r0 = (lane >> 4) << 2;
#pragma unroll
    for (int n = 0; n < NT_TILES; ++n) {
        int col = n * 16 + (lane & 15);
        float bv = bias[col];
#pragma unroll
        for (int q = 0; q < 4; ++q)
            Ld[(r0 + q) * ld + col] = fmaxf(acc[n][q] + bv, 0.f);
    }
}

// ---------------- Bucketed CSR: one pass does count + fill ----------------

__global__ __launch_bounds__(256) void k_fill(const int* __restrict__ src, const int* __restrict__ dst,
                                              const int* __restrict__ etype, int* __restrict__ cnt,
                                              int* __restrict__ eidx, int E) {
    int e = blockIdx.x * 256 + threadIdx.x;
    if (e < E) {
        int d = dst[e];
        int p = atomicAdd(&cnt[d], 1);
        if (p < CAP) eidx[(size_t)d * CAP + p] = src[e] * 4 + etype[e];
    }
}

// ---------------- Weight prep: split + frag-swizzle all B matrices ----------------

__global__ __launch_bounds__(256) void k_wprep(
    const float* __restrict__ W1, const float* __restrict__ W2,
    const float* __restrict__ W3, const float* __restrict__ Wu1,
    const float* __restrict__ Wu2, const float* __restrict__ Wu3,
    short* __restrict__ Phi, short* __restrict__ Plo)
{
    int pair = blockIdx.x;
    const float* src; int KS, NTl, fragbase, ncol;
    if (pair < 16) {
        int r = pair >> 2, mat = pair & 3;
        if (mat == 0)      { src = W1  + (size_t)r * (D * H);       KS = 4; NTl = 4; fragbase = r * PREL + 0;  ncol = 64;  }
        else if (mat == 1) { src = W2  + (size_t)r * (H * H);       KS = 2; NTl = 4; fragbase = r * PREL + 16; ncol = 64;  }
        else if (mat == 2) { src = W3  + (size_t)r * (H * D);       KS = 2; NTl = 8; fragbase = r * PREL + 24; ncol = 128; }
        else               { src = Wu1 + (size_t)(r + 1) * D * H;   KS = 4; NTl = 4; fragbase = r * PREL + 40; ncol = 64;  }
    } else {
        int mat = pair - 16;
        if (mat == 0)      { src = Wu1; KS = 4; NTl = 4; fragbase = UBASE + 0;  ncol = 64;  }  // rows 0..127
        else if (mat == 1) { src = Wu2; KS = 2; NTl = 4; fragbase = UBASE + 16; ncol = 64;  }
        else               { src = Wu3; KS = 2; NTl = 8; fragbase = UBASE + 24; ncol = 128; }
    }
    int nf = NTl * KS;
    for (int u = threadIdx.x; u < nf * 64; u += 256) {
        int f = u >> 6, lane = u & 63;
        int n = f / KS, ks = f - n * KS;
        int col = n * 16 + (lane & 15);
        int k0 = ks * 32 + ((lane >> 4) << 3);
        size_t dstp = (((size_t)(fragbase + f)) * 64 + (size_t)lane) * 8;
#pragma unroll
        for (int i = 0; i < 8; ++i) {
            short h, l;
            split1(src[(size_t)(k0 + i) * ncol + col], h, l);
            Phi[dstp + i] = h;
            Plo[dstp + i] = l;
        }
    }
}

// ---------------- Stage A: per-(tile, relation) message MLP + Wu1 fold ----------------
// B staged via global_load_lds (R14); U output now bf16 (RNE) -> halves U write
// and the gather's read bytes.

__global__ __launch_bounds__(256, 2) void k_mlp_rel(
    const float* __restrict__ X,
    const float* __restrict__ b1, const float* __restrict__ b2, const float* __restrict__ b3,
    const short* __restrict__ Phi, const short* __restrict__ Plo,
    unsigned short* __restrict__ U, int N, int tiles)
{
    __shared__ float Bsh[NT * LDC];     // per-wave 16-row strips
    __shared__ short BbH[16 * PFRAG];   // staged B hi (<= 16 frags/layer)
    __shared__ short BbL[16 * PFRAG];   // staged B lo

    const int tid = threadIdx.x;
    const int lane = tid & 63;
    const int w = tid >> 6;
    const int m16 = w * 16;
    const int r = blockIdx.x / tiles;          // relation-major
    const int n0 = (blockIdx.x - r * tiles) * NT;

    const short* PH = Phi + (size_t)(r * PREL) * PFRAG;
    const short* PL = Plo + (size_t)(r * PREL) * PFRAG;
    const float* b1r = b1 + r * H;
    const float* b2r = b2 + r * H;
    const float* b3r = b3 + r * D;

    float* Ws = &Bsh[m16 * LDC];   // this wave's strip

    // issue W1 staging first so it overlaps the X register staging below
    stage_B(PH, PL, BbH, BbL, 16, w, lane);

    // stage X A-fragments direct from global into registers, split once
    bf16x8 ahx[4], alx[4];
    {
        int row = n0 + m16 + (lane & 15);
        const float* xp = X + (size_t)row * D + ((lane >> 4) << 3);
        bool ok = (row < N);
#pragma unroll
        for (int ks = 0; ks < 4; ++ks) {
            float x8[8];
            if (ok) {
                *(float4*)&x8[0] = *(const float4*)(xp + ks * 32);
                *(float4*)&x8[4] = *(const float4*)(xp + ks * 32 + 4);
            } else {
#pragma unroll
                for (int i = 0; i < 8; ++i) x8[i] = 0.f;
            }
            split8(x8, ahx[ks], alx[ks]);
        }
    }
    __syncthreads();   // W1 staged (syncthreads drains vmcnt)

    // layer 1: X(16x128) @ W1(128x64) — A regs, B LDS
    f32x4 acc[8];
#pragma unroll
    for (int n = 0; n < 4; ++n) acc[n] = (f32x4){0.f, 0.f, 0.f, 0.f};
    mfma_layer_regA_ldsB<4, 4>(ahx, alx, BbH, BbL, lane, acc);
    store_C_lds<4>(acc, b1r, Ws, LDC, lane);   // H1
    __syncthreads();   // all waves done reading W1

    // layer 2: H1(16x64) @ W2(64x64)
    stage_B(PH + 16 * PFRAG, PL + 16 * PFRAG, BbH, BbL, 8, w, lane);
    __syncthreads();
#pragma unroll
    for (int n = 0; n < 4; ++n) acc[n] = (f32x4){0.f, 0.f, 0.f, 0.f};
    mfma_layer_ldsB<4, 2>(Ws, LDC, BbH, BbL, lane, acc);
    store_C_lds<4>(acc, b2r, Ws, LDC, lane);   // H2
    __syncthreads();

    // layer 3: H2(16x64) @ W3(64x128), relu -> T
    stage_B(PH + 24 * PFRAG, PL + 24 * PFRAG, BbH, BbL, 16, w, lane);
    __syncthreads();
#pragma unroll
    for (int n = 0; n < 8; ++n) acc[n] = (f32x4){0.f, 0.f, 0.f, 0.f};
    mfma_layer_ldsB<8, 2>(Ws, LDC, BbH, BbL, lane, acc);
    store_C_lds<8>(acc, b3r, Ws, LDC, lane);   // T
    __syncthreads();

    // U projection: T(16x128) @ Wu1_{r+1}(128x64), store bf16 (RNE)
    stage_B(PH + 40 * PFRAG, PL + 40 * PFRAG, BbH, BbL, 16, w, lane);
    __syncthreads();
#pragma unroll
    for (int n = 0; n < 4; ++n) acc[n] = (f32x4){0.f, 0.f, 0.f, 0.f};
    mfma_layer_ldsB<4, 4>(Ws, LDC, BbH, BbL, lane, acc);
    {
        int r0 = (lane >> 4) << 2;
#pragma unroll
        for (int n = 0; n < 4; ++n) {
            int col = n * 16 + (lane & 15);
#pragma unroll
            for (int q = 0; q < 4; ++q) {
                int node = n0 + m16 + r0 + q;
                if (node < N)
                    U[((size_t)node * R + r) * H + col] = f2bf_rne(acc[n][q]);
            }
        }
    }
}

// ---------------- Stage B: gather S[n] = sum over in-edges of U[src*4+rel] ----------------
// U rows are 64 bf16 = 128 B; 32 lanes x uint (2 bf16). 16 edges in flight/wave.

__global__ __launch_bounds__(256) void k_gather(
    const unsigned int* __restrict__ U32,   // U viewed as uint pairs
    const int* __restrict__ cnt, const int* __restrict__ eidx,
    float* __restrict__ S, int N)
{
    const int wid = threadIdx.x >> 6, lane = threadIdx.x & 63;
    const int n = blockIdx.x * 4 + wid;
    if (n >= N) return;
    int g = cnt[n]; if (g > CAP) g = CAP;
    const int* ep = eidx + (size_t)n * CAP;
    const int half = lane >> 5;      // which edge of each pair
    const int c2 = lane & 31;        // uint column (2 bf16)
    float ax = 0.f, ay = 0.f;
    for (int base = 0; base < g; base += 64) {
        int m = g - base; if (m > 64) m = 64;
        int v = 0;
        if (lane < m) v = ep[base + lane];
        for (int j0 = 0; j0 < m; j0 += 16) {
            int lim = m - j0; if (lim > 16) lim = 16;
            unsigned t[8];
#pragma unroll
            for (int p = 0; p < 8; ++p) {
                int vi = __shfl(v, j0 + 2 * p + half);
                bool ok = (2 * p + half) < lim;
                t[p] = ok ? U32[(size_t)vi * 32 + c2] : 0u;   // 16 edges in flight
            }
#pragma unroll
            for (int p = 0; p < 8; ++p) {
                ax += __uint_as_float(t[p] << 16);            // low bf16
                ay += __uint_as_float(t[p] & 0xffff0000u);    // high bf16
            }
        }
    }
    ax += __shfl_xor(ax, 32);
    ay += __shfl_xor(ay, 32);
    if (half == 0)
        *(float2*)&S[(size_t)n * H + (c2 << 1)] = make_float2(ax, ay);
}

// ---------------- Stage C: updater MLP + select (split-bf16 MFMA, barrier-free) ----------------

__global__ __launch_bounds__(256, 4) void k_upd(
    const float* __restrict__ X, const float* __restrict__ S,
    const int* __restrict__ cnt, const int* __restrict__ node_type,
    const short* __restrict__ Phi, const short* __restrict__ Plo,
    const float* __restrict__ bu1, const float* __restrict__ bu2, const float* __restrict__ bu3,
    float* __restrict__ out, int N)
{
    __shared__ float Hsh[NT * LDC];   // per-wave strips (H1/H2)

    const int tid = threadIdx.x;
    const int lane = tid & 63;
    const int w = tid >> 6;
    const int m16 = w * 16;
    const int n0 = blockIdx.x * NT;

    const short* PH = Phi + (size_t)UBASE * PFRAG;
    const short* PL = Plo + (size_t)UBASE * PFRAG;

    float* Ws = &Hsh[m16 * LDC];

    // stage chunk0 = relu(x) * (indeg > 0) direct into register A-fragments
    bf16x8 ahx[4], alx[4];
    {
        int row = n0 + m16 + (lane & 15);
        bool ok = (row < N) && (cnt[row] > 0);
        const float* xp = X + (size_t)row * D + ((lane >> 4) << 3);
#pragma unroll
        for (int ks = 0; ks < 4; ++ks) {
            float x8[8];
            if (ok) {
                float4 a = *(const float4*)(xp + ks * 32);
                float4 b = *(const float4*)(xp + ks * 32 + 4);
                a = relu4(a); b = relu4(b);
                *(float4*)&x8[0] = a;
                *(float4*)&x8[4] = b;
            } else {
#pragma unroll
                for (int i = 0; i < 8; ++i) x8[i] = 0.f;
            }
            split8(x8, ahx[ks], alx[ks]);
        }
    }

    // layer 1: chunk0 @ Wu1[0:128] + S + bu1, relu -> H1
    f32x4 acc[8];
#pragma unroll
    for (int n = 0; n < 4; ++n) acc[n] = (f32x4){0.f, 0.f, 0.f, 0.f};
    mfma_layer_regA<4, 4>(ahx, alx, PH, PL, lane, acc);
    {
        int r0 = (lane >> 4) << 2;
#pragma unroll
        for (int n = 0; n < 4; ++n) {
            int col = n * 16 + (lane & 15);
            float bv = bu1[col];
#pragma unroll
            for (int q = 0; q < 4; ++q) {
                int node = n0 + m16 + r0 + q;
                float sv = (node < N) ? S[(size_t)node * H + col] : 0.f;
                Ws[(r0 + q) * LDC + col] = fmaxf(acc[n][q] + bv + sv, 0.f);
            }
        }
    }

    // layer 2: H1 @ Wu2, relu -> H2 (in place)
#pragma unroll
    for (int n = 0; n < 4; ++n) acc[n] = (f32x4){0.f, 0.f, 0.f, 0.f};
    mfma_layer<4, 2>(Ws, LDC, PH + (size_t)16 * PFRAG, PL + (size_t)16 * PFRAG, lane, acc);
    store_C_lds<4>(acc, bu2, Ws, LDC, lane);

    // layer 3: H2 @ Wu3 (linear) + select by node_type
#pragma unroll
    for (int n = 0; n < 8; ++n) acc[n] = (f32x4){0.f, 0.f, 0.f, 0.f};
    mfma_layer<8, 2>(Ws, LDC, PH + (size_t)24 * PFRAG, PL + (size_t)24 * PFRAG, lane, acc);
    {
        int r0 = (lane >> 4) << 2;
#pragma unroll
        for (int q = 0; q < 4; ++q) {
            int node = n0 + m16 + r0 + q;
            if (node >= N) continue;
            int t = node_type[node];
#pragma unroll
            for (int n = 0; n < 8; ++n) {
                int col = n * 16 + (lane & 15);
                float o = (t <= 1) ? (acc[n][q] + bu3[col])
                                   : X[(size_t)node * D + col];
                out[(size_t)node * D + col] = o;
            }
        }
    }
}

extern "C" void kernel_launch(void* const* d_in, const int* in_sizes, int n_in,
                              void* d_out, int out_size, void* d_ws, size_t ws_size,
                              hipStream_t stream) {
    const float* X     = (const float*)d_in[0];
    const int*   src   = (const int*)d_in[1];
    const int*   dst   = (const int*)d_in[2];
    const int*   etype = (const int*)d_in[3];
    const int*   ntype = (const int*)d_in[4];
    const float* W1    = (const float*)d_in[5];
    const float* b1    = (const float*)d_in[6];
    const float* W2    = (const float*)d_in[7];
    const float* b2    = (const float*)d_in[8];
    const float* W3    = (const float*)d_in[9];
    const float* b3    = (const float*)d_in[10];
    const float* Wu1   = (const float*)d_in[11];
    const float* bu1   = (const float*)d_in[12];
    const float* Wu2   = (const float*)d_in[13];
    const float* bu2   = (const float*)d_in[14];
    const float* Wu3   = (const float*)d_in[15];
    const float* bu3   = (const float*)d_in[16];
    float* out = (float*)d_out;

    const int N = in_sizes[4];
    const int E = in_sizes[1];

    // workspace layout
    unsigned short* U = (unsigned short*)d_ws;        // N*R*H bf16 (25.6 MB)
    float* S    = (float*)(U + (size_t)N * R * H);    // N*H floats (12.8 MB)
    int* cnt    = (int*)(S + (size_t)N * H);          // N
    int* eidx   = cnt + N;                            // N*CAP ints (25.6 MB)
    short* Phi  = (short*)(eidx + (size_t)N * CAP);   // NFRAG*PFRAG shorts
    short* Plo  = Phi + (size_t)NFRAG * PFRAG;

    hipMemsetAsync(cnt, 0, (size_t)N * sizeof(int), stream);

    int eb = (E + 255) / 256;
    k_fill<<<eb, 256, 0, stream>>>(src, dst, etype, cnt, eidx, E);
    k_wprep<<<19, 256, 0, stream>>>(W1, W2, W3, Wu1, Wu2, Wu3, Phi, Plo);

    int tiles = (N + NT - 1) / NT;
    k_mlp_rel<<<tiles * R, 256, 0, stream>>>(X, b1, b2, b3, Phi, Plo, U, N, tiles);
    k_gather<<<(N + 3) / 4, 256, 0, stream>>>((const unsigned int*)U, cnt, eidx, S, N);
    k_upd<<<tiles, 256, 0, stream>>>(X, S, cnt, ntype, Phi, Plo, bu1, bu2, bu3, out, N);
}